// Round 14
// baseline (1294.397 us; speedup 1.0000x reference)
//
#include <hip/hip_runtime.h>
#include <math.h>

#define L_  28
#define H_  1024
#define NH_ 8
#define KVH_ 4
#define HD_ 128
#define I_  3072
#define VC_ 4096
#define B_  4
#define S_  512
#define EPS_ 1e-6f

// ---- workspace layout (float offsets) ----
#define WS_HA    0            // [4][1024] h after attn-input fold (h3)
#define WS_HB    4096         // [4][1024] h after mlp-input fold (h4)
#define WS_XFU   8192         // [4][1024] unscaled final-normed x
#define WS_SSQ1  12288        // [32 ks][4 b] ssq partials of h3
#define WS_SSQ2  12416        // [32 ks][4 b] ssq partials of h4
#define WS_SSQF  12544        // [32 ks][4 b] ssq partials of h_final
#define WS_QKVP  12672        // [32][4][2048]
#define WS_ATTO  274816       // [16 bg][2 r][16 c][128]
#define WS_ATML  340352       // [16 bg][2 r][16 c][2]
#define WS_GUP   472448       // [32][4][6144]
#define WS_DWP   1258880      // [48][4][1024]
#define WS_HDP   1455488      // [32][4][4096]

typedef float v4f __attribute__((ext_vector_type(4)));

__device__ __forceinline__ float4 ntld4(const float* p) {
    v4f r = __builtin_nontemporal_load(reinterpret_cast<const v4f*>(p));
    return make_float4(r.x, r.y, r.z, r.w);
}
__device__ __forceinline__ void ntst4(float* p, float4 v) {
    v4f r = {v.x, v.y, v.z, v.w};
    __builtin_nontemporal_store(r, reinterpret_cast<v4f*>(p));
}

__device__ __forceinline__ float wave_reduce_sum(float v) {
    #pragma unroll
    for (int off = 32; off; off >>= 1) v += __shfl_down(v, off);
    return v;
}
__device__ __forceinline__ float wave_reduce_max(float v) {
    #pragma unroll
    for (int off = 32; off; off >>= 1) v = fmaxf(v, __shfl_down(v, off));
    return v;
}

// ---------------- GEMV core: NT weight preload -> prologue -> FMA -> LDS reduce -> store ----------------
template<int RPW, int NTOT, typename F>
__device__ __forceinline__ void gemv_core(
    const float* __restrict__ W, int ldw, int wcol0, int k0,
    float* __restrict__ xsl, float4* __restrict__ accbuf,
    float* __restrict__ pp, int colblk, int ks, F&& prologue)
{
    const int t = threadIdx.x;
    const int wv = t >> 6, lane = t & 63;
    const float* Wp = W + (size_t)(k0 + wv * RPW) * ldw + wcol0 + lane * 4;
    float4 wreg[RPW];
    #pragma unroll
    for (int i = 0; i < RPW; i++) wreg[i] = ntld4(Wp + (size_t)i * ldw);
    prologue();   // fills xsl; ends with __syncthreads()
    const float4* xs4 = (const float4*)xsl;
    float4 a0 = {0,0,0,0}, a1 = {0,0,0,0}, a2 = {0,0,0,0}, a3 = {0,0,0,0};
    #pragma unroll
    for (int i = 0; i < RPW; i++) {
        float4 w4 = wreg[i];
        float4 xb = xs4[wv * RPW + i];
        a0.x += w4.x * xb.x; a0.y += w4.y * xb.x; a0.z += w4.z * xb.x; a0.w += w4.w * xb.x;
        a1.x += w4.x * xb.y; a1.y += w4.y * xb.y; a1.z += w4.z * xb.y; a1.w += w4.w * xb.y;
        a2.x += w4.x * xb.z; a2.y += w4.y * xb.z; a2.z += w4.z * xb.z; a2.w += w4.w * xb.z;
        a3.x += w4.x * xb.w; a3.y += w4.y * xb.w; a3.z += w4.z * xb.w; a3.w += w4.w * xb.w;
    }
    accbuf[(wv * 64 + lane) * 4 + 0] = a0;
    accbuf[(wv * 64 + lane) * 4 + 1] = a1;
    accbuf[(wv * 64 + lane) * 4 + 2] = a2;
    accbuf[(wv * 64 + lane) * 4 + 3] = a3;
    __syncthreads();
    const int l2 = t >> 2, b2 = t & 3;
    float4 s0 = accbuf[(0 * 64 + l2) * 4 + b2];
    float4 s1 = accbuf[(1 * 64 + l2) * 4 + b2];
    float4 s2 = accbuf[(2 * 64 + l2) * 4 + b2];
    float4 s3 = accbuf[(3 * 64 + l2) * 4 + b2];
    float4 s;
    s.x = s0.x + s1.x + s2.x + s3.x;
    s.y = s0.y + s1.y + s2.y + s3.y;
    s.z = s0.z + s1.z + s2.z + s3.z;
    s.w = s0.w + s1.w + s2.w + s3.w;
    *(float4*)(pp + ((size_t)ks * 4 + b2) * NTOT + colblk * 256 + l2 * 4) = s;
}

// ---------------- qkv (fused embed for l==0; fold+norm prologue): grid (8, 32) ----------------
template<bool FIRST>
__global__ __launch_bounds__(256) void k_qkv(
    const float* __restrict__ hPrev, const float* __restrict__ dwp,
    const int* __restrict__ cb0, const int* __restrict__ cb1,
    const float* __restrict__ trail, const float* __restrict__ cb0e,
    const float* __restrict__ cpe,
    const float* __restrict__ ln1,
    const float* __restrict__ Wq, const float* __restrict__ Wk,
    const float* __restrict__ Wv,
    float* __restrict__ hA, float* __restrict__ ssqp1, float* __restrict__ qkvp)
{
    __shared__ float xsl[128];
    __shared__ float4 accbuf[1024];
    __shared__ float sred[128];
    const int t = threadIdx.x;
    const int ks = blockIdx.y, k0 = ks * 32, cb = blockIdx.x;
    const float* W; int ldw, wcol0;
    if (cb < 4)      { W = Wq; ldw = 1024; wcol0 = cb * 256; }
    else if (cb < 6) { W = Wk; ldw = 512;  wcol0 = (cb - 4) * 256; }
    else             { W = Wv; ldw = 512;  wcol0 = (cb - 6) * 256; }
    gemv_core<8, 2048>(W, ldw, wcol0, k0, xsl, accbuf, qkvp, cb, ks, [&]() {
        if (t < 128) {
            const int row = t >> 2, b = t & 3;
            const int gr = k0 + row;
            float hn;
            if (FIRST) {
                hn = cb0e[(size_t)cb0[b] * 1024 + gr] + trail[b * 1024 + gr];
                #pragma unroll
                for (int j = 0; j < 15; j++)
                    hn += cpe[((size_t)j * 4096 + cb1[b * 15 + j]) * 1024 + gr];
            } else {
                hn = hPrev[b * 1024 + gr];
                #pragma unroll 16
                for (int c = 0; c < 48; c++) hn += dwp[(size_t)(c * 4 + b) * 1024 + gr];
            }
            sred[t] = hn * hn;
            xsl[row * 4 + b] = hn * ln1[gr];
            if (cb == 0) hA[b * 1024 + gr] = hn;
        }
        __syncthreads();
        if (cb == 0 && t < 4) {
            float s = 0.f;
            #pragma unroll
            for (int r = 0; r < 32; r++) s += sred[r * 4 + t];
            ssqp1[ks * 4 + t] = s;
        }
    });
}

// ---------------- attention flash chunk: grid (16 bg, 16 c), block 256 ----------------
__global__ __launch_bounds__(256) void k_attn(
    const float* __restrict__ qkvp, const float* __restrict__ ssqp1,
    const float* __restrict__ qnw, const float* __restrict__ knw,
    const float* __restrict__ kin, const float* __restrict__ vin,
    float* __restrict__ kout, float* __restrict__ vout,
    const int* __restrict__ pos,
    float* __restrict__ opart, float* __restrict__ mlpart)
{
    __shared__ float Kl[33][129];
    __shared__ float Vl[33][129];
    __shared__ float ql[2][128];
    __shared__ float sc[2][36];
    __shared__ float red[8];
    __shared__ float rms1sh;

    const int t = threadIdx.x;
    const int bg = blockIdx.x, b = bg >> 2, g = bg & 3;
    const int c = blockIdx.y;           // 0..15
    const int lane = t & 63;
    const int r = t >> 7, d = t & 127;
    const float scale = 0.088388347648318447f;  // 1/sqrt(128)

    if (c == 15 && t == 0) {
        float s = 0.f;
        #pragma unroll
        for (int i = 0; i < 32; i++) s += ssqp1[i * 4 + b];
        rms1sh = rsqrtf(s * (1.f / 1024.f) + EPS_);
    }

    const float posf = (float)pos[b];
    const int j = d & 63;
    const float invf = exp2f(-(float)j * 0.31143075889569021f);  // 1e6^(-j/64)
    const float ang = posf * invf;
    const float cs = cosf(ang), sn = sinf(ang);
    const int pd = (d < 64) ? d + 64 : d - 64;

    // q: reduce 32 split-K chunks (UNSCALED -- head-norm is scale-invariant)
    float qraw = 0.f;
    {
        const int n = (2 * g + r) * 128 + d;
        #pragma unroll
        for (int cc = 0; cc < 32; cc++) qraw += qkvp[((size_t)cc * 4 + b) * 2048 + n];
    }
    ql[r][d] = qraw;
    float ssq = wave_reduce_sum(qraw * qraw);
    if (lane == 0) red[t >> 6] = ssq;
    __syncthreads();  // (A)
    const float rms_q = rsqrtf((red[r * 2] + red[r * 2 + 1]) * (1.f / 128.f) + EPS_);
    float qv = qraw * rms_q * qnw[d];
    float qp = ql[r][pd] * rms_q * qnw[pd];
    float qro = qv * cs + ((d < 64) ? -qp : qp) * sn;

    // new k/v: only chunk 15
    float kvraw = 0.f;
    if (c == 15) {
        const int base = (t < 128) ? (1024 + g * 128 + d) : (1536 + g * 128 + d);
        #pragma unroll
        for (int cc = 0; cc < 32; cc++) kvraw += qkvp[((size_t)cc * 4 + b) * 2048 + base];
    }
    float kss = wave_reduce_sum((t < 128) ? kvraw * kvraw : 0.f);
    __syncthreads();  // (B)
    ql[r][d] = qro;
    if (lane == 0 && t < 128) red[t >> 6] = kss;
    if (c == 15) { if (t < 128) Kl[32][d] = kvraw; else Vl[32][d] = kvraw; }
    __syncthreads();  // (C)
    float newkv = 0.f;
    if (c == 15) {
        if (t < 128) {
            const float rms_k = rsqrtf((red[0] + red[1]) * (1.f / 128.f) + EPS_);
            float kv_ = Kl[32][d] * rms_k * knw[d];
            float kp  = Kl[32][pd] * rms_k * knw[pd];
            newkv = kv_ * cs + ((d < 64) ? -kp : kp) * sn;
        } else {
            newkv = Vl[32][d] * rms1sh;      // deferred rms1 on V
        }
    }
    __syncthreads();  // (D)
    const size_t out_bg = (size_t)bg * (513 * 128);
    if (c == 15) {
        if (t < 128) { Kl[32][d] = newkv; kout[out_bg + 512 * 128 + d] = newkv; }
        else         { Vl[32][d] = newkv; vout[out_bg + 512 * 128 + d] = newkv; }
    }

    // KV tile (32 keys) load into LDS + copy to output cache (NT float4)
    const size_t in_bg = (size_t)bg * (512 * 128);
    const int s0 = c * 32;
    #pragma unroll
    for (int i = 0; i < 4; i++) {
        int f4 = i * 256 + t;
        int row = f4 >> 5, d0 = (f4 & 31) * 4;
        float4 k4 = ntld4(kin + in_bg + (size_t)(s0 + row) * 128 + d0);
        float4 v4 = ntld4(vin + in_bg + (size_t)(s0 + row) * 128 + d0);
        Kl[row][d0] = k4.x; Kl[row][d0 + 1] = k4.y; Kl[row][d0 + 2] = k4.z; Kl[row][d0 + 3] = k4.w;
        Vl[row][d0] = v4.x; Vl[row][d0 + 1] = v4.y; Vl[row][d0 + 2] = v4.z; Vl[row][d0 + 3] = v4.w;
        ntst4(kout + out_bg + (size_t)(s0 + row) * 128 + d0, k4);
        ntst4(vout + out_bg + (size_t)(s0 + row) * 128 + d0, v4);
    }
    __syncthreads();  // (E)

    // scores
    const int nk = (c == 15) ? 33 : 32;
    const int si = d;
    float sv = -1e30f;
    if (si < nk) {
        float a = 0.f;
        #pragma unroll 8
        for (int dd = 0; dd < 128; dd++) a += ql[r][dd] * Kl[si][dd];
        sv = a * scale;
    }
    float mv = wave_reduce_max(sv);
    if (lane == 0) red[t >> 6] = mv;
    __syncthreads();
    const float m = fmaxf(red[r * 2], red[r * 2 + 1]);
    float p = (si < nk) ? expf(sv - m) : 0.f;
    if (si < nk) sc[r][si] = p;
    float lsum = wave_reduce_sum(p);
    __syncthreads();
    if (lane == 0) red[t >> 6] = lsum;
    __syncthreads();
    const float lr = red[r * 2] + red[r * 2 + 1];
    if (d == 0) {
        mlpart[(size_t)((bg * 2 + r) * 16 + c) * 2 + 0] = m;
        mlpart[(size_t)((bg * 2 + r) * 16 + c) * 2 + 1] = lr;
    }
    float o = 0.f;
    for (int s2 = 0; s2 < nk; s2++) o += sc[r][s2] * Vl[s2][d];
    opart[(size_t)((bg * 2 + r) * 16 + c) * 128 + d] = o;
}

// ---------------- gate/up with FUSED flash-combine + oproj slice: grid (8, 32) ----------------
// Each block: (1) combine full ao[4][1024] into LDS; (2) compute its 32-col slice of the
// Wo GEMV; (3) h4 = hA + slice, ln2-norm; (4) 3 gate/up column-units, double-buffered.
__global__ __launch_bounds__(256) void k_gateup(
    const float* __restrict__ hA,
    const float* __restrict__ atto, const float* __restrict__ atml,
    const float* __restrict__ Wo_l, const float* __restrict__ ln2,
    const float* __restrict__ Wg_l, const float* __restrict__ Wu_l,
    float* __restrict__ hB, float* __restrict__ ssqp2, float* __restrict__ gup)
{
    __shared__ float aosl[4][1024];      // 16 KB combined attention output
    __shared__ float redsl[8][32][4];    // 4 KB oproj partial
    __shared__ float xsl[128];
    __shared__ float4 accbuf[1024];      // 16 KB
    __shared__ float sred[128];
    const int t = threadIdx.x;
    const int ks = blockIdx.y, k0 = ks * 32, bx = blockIdx.x;
    const int wv = t >> 6, lane = t & 63;
    const int u0 = bx * 3;

    // ---- step 1: flash-combine ao (thread t: batch t>>6, 16 dh values at (t&63)*16) ----
    {
        const int b = t >> 6;
        const int kb = (t & 63) * 16;
        const int head = kb >> 7, dh0 = kb & 127;
        const int g = head >> 1, rr = head & 1;
        const size_t base = (size_t)((b * 4 + g) * 2 + rr) * 16;
        float mc[16], lc[16], M = -1e30f;
        #pragma unroll
        for (int cc = 0; cc < 16; cc++) {
            mc[cc] = atml[(base + cc) * 2];
            lc[cc] = atml[(base + cc) * 2 + 1];
            M = fmaxf(M, mc[cc]);
        }
        float Ls = 0.f, o[16];
        #pragma unroll
        for (int i = 0; i < 16; i++) o[i] = 0.f;
        #pragma unroll
        for (int cc = 0; cc < 16; cc++) {
            const float wch = expf(mc[cc] - M);
            Ls += lc[cc] * wch;
            const float* ap = atto + (base + cc) * 128 + dh0;
            #pragma unroll
            for (int i = 0; i < 16; i++) o[i] += ap[i] * wch;
        }
        const float inv = 1.f / Ls;
        #pragma unroll
        for (int i = 0; i < 16; i++) aosl[b][kb + i] = o[i] * inv;
    }
    __syncthreads();

    // ---- step 2: oproj slice, cols k0..k0+32, split over 8 k-groups ----
    {
        const int c = t & 31, kg = t >> 5;
        const int col = k0 + c;
        float a0 = 0.f, a1 = 0.f, a2 = 0.f, a3 = 0.f;
        const float* Wp = Wo_l + (size_t)(kg * 128) * 1024 + col;
        #pragma unroll 8
        for (int k = 0; k < 128; k++) {
            const float w = Wp[(size_t)k * 1024];
            const int ka = kg * 128 + k;
            a0 += aosl[0][ka] * w; a1 += aosl[1][ka] * w;
            a2 += aosl[2][ka] * w; a3 += aosl[3][ka] * w;
        }
        redsl[kg][c][0] = a0; redsl[kg][c][1] = a1;
        redsl[kg][c][2] = a2; redsl[kg][c][3] = a3;
    }
    __syncthreads();

    // ---- step 3: h4 = hA + oproj, ln2-norm into xsl; publish hB/ssq (bx==0) ----
    if (t < 128) {
        const int row = t >> 2, b = t & 3;
        const int gr = k0 + row;
        float op = 0.f;
        #pragma unroll
        for (int kg = 0; kg < 8; kg++) op += redsl[kg][row][b];
        const float hn = hA[b * 1024 + gr] + op;
        sred[t] = hn * hn;
        xsl[row * 4 + b] = hn * ln2[gr];
        if (bx == 0) hB[b * 1024 + gr] = hn;
    }
    __syncthreads();
    if (bx == 0 && t < 4) {
        float s = 0.f;
        #pragma unroll
        for (int r = 0; r < 32; r++) s += sred[r * 4 + t];
        ssqp2[ks * 4 + t] = s;
    }

    // ---- step 4: 3 gate/up units, double-buffered NT weight fetch ----
    float4 wA[8], wB[8];
    {
        const float* Wp = ((u0 < 12) ? (Wg_l + u0 * 256) : (Wu_l + (u0 - 12) * 256))
                          + (size_t)(k0 + wv * 8) * 3072 + lane * 4;
        #pragma unroll
        for (int i = 0; i < 8; i++) wA[i] = ntld4(Wp + (size_t)i * 3072);
    }
    const float4* xs4 = (const float4*)xsl;
    #pragma unroll
    for (int j = 0; j < 3; j++) {
        const int u = u0 + j;
        if (j < 2) {   // prefetch next unit before the LDS reduce
            const int un = u0 + j + 1;
            const float* Wpn = ((un < 12) ? (Wg_l + un * 256) : (Wu_l + (un - 12) * 256))
                               + (size_t)(k0 + wv * 8) * 3072 + lane * 4;
            float4* wn = (j == 0) ? wB : wA;
            #pragma unroll
            for (int i = 0; i < 8; i++) wn[i] = ntld4(Wpn + (size_t)i * 3072);
        }
        const float4* wc = (j == 1) ? wB : wA;
        float4 a0 = {0,0,0,0}, a1 = {0,0,0,0}, a2 = {0,0,0,0}, a3 = {0,0,0,0};
        #pragma unroll
        for (int i = 0; i < 8; i++) {
            float4 w4 = wc[i];
            float4 xb = xs4[wv * 8 + i];
            a0.x += w4.x * xb.x; a0.y += w4.y * xb.x; a0.z += w4.z * xb.x; a0.w += w4.w * xb.x;
            a1.x += w4.x * xb.y; a1.y += w4.y * xb.y; a1.z += w4.z * xb.y; a1.w += w4.w * xb.y;
            a2.x += w4.x * xb.z; a2.y += w4.y * xb.z; a2.z += w4.z * xb.z; a2.w += w4.w * xb.z;
            a3.x += w4.x * xb.w; a3.y += w4.y * xb.w; a3.z += w4.z * xb.w; a3.w += w4.w * xb.w;
        }
        accbuf[(wv * 64 + lane) * 4 + 0] = a0;
        accbuf[(wv * 64 + lane) * 4 + 1] = a1;
        accbuf[(wv * 64 + lane) * 4 + 2] = a2;
        accbuf[(wv * 64 + lane) * 4 + 3] = a3;
        __syncthreads();
        const int l2 = t >> 2, b2 = t & 3;
        float4 s0 = accbuf[(0 * 64 + l2) * 4 + b2];
        float4 s1 = accbuf[(1 * 64 + l2) * 4 + b2];
        float4 s2 = accbuf[(2 * 64 + l2) * 4 + b2];
        float4 s3 = accbuf[(3 * 64 + l2) * 4 + b2];
        float4 s;
        s.x = s0.x + s1.x + s2.x + s3.x;
        s.y = s0.y + s1.y + s2.y + s3.y;
        s.z = s0.z + s1.z + s2.z + s3.z;
        s.w = s0.w + s1.w + s2.w + s3.w;
        const int ucol0 = (u < 12) ? u * 256 : 3072 + (u - 12) * 256;
        *(float4*)(gup + ((size_t)ks * 4 + b2) * 6144 + ucol0 + l2 * 4) = s;
        __syncthreads();
    }
}

// ---------------- down: deferred rms2 before SiLU. grid (4, 48) ----------------
__global__ __launch_bounds__(256) void k_down(
    const float* __restrict__ gup, const float* __restrict__ ssqp2,
    const float* __restrict__ Wd_l, float* __restrict__ dwp)
{
    __shared__ float xsl[256];
    __shared__ float4 accbuf[1024];
    __shared__ float rmsb[4];
    const int t = threadIdx.x;
    const int ks = blockIdx.y, k0 = ks * 64, cb = blockIdx.x;
    gemv_core<16, 1024>(Wd_l, 1024, cb * 256, k0, xsl, accbuf, dwp, cb, ks, [&]() {
        if (t < 4) {
            float s = 0.f;
            #pragma unroll
            for (int i = 0; i < 32; i++) s += ssqp2[i * 4 + t];
            rmsb[t] = rsqrtf(s * (1.f / 1024.f) + EPS_);
        }
        __syncthreads();
        const int b = t >> 6, kk = t & 63;
        const float rm = rmsb[b];
        float gg = 0.f, uu = 0.f;
        #pragma unroll 8
        for (int cc = 0; cc < 32; cc++) {
            gg += gup[((size_t)cc * 4 + b) * 6144 + k0 + kk];
            uu += gup[((size_t)cc * 4 + b) * 6144 + 3072 + k0 + kk];
        }
        gg *= rm; uu *= rm;
        xsl[kk * 4 + b] = gg / (1.f + expf(-gg)) * uu;
        __syncthreads();
    });
}

// ---------------- head: fold h_final rows; UNSCALED x = h*normw. grid (16, 32) ----------------
__global__ __launch_bounds__(256) void k_head(
    const float* __restrict__ hB, const float* __restrict__ dwp,
    const float* __restrict__ normw, const float* __restrict__ headw,
    float* __restrict__ xfu, float* __restrict__ ssqpF, float* __restrict__ hdp)
{
    __shared__ float xsl[128];
    __shared__ float4 accbuf[1024];
    __shared__ float sred[128];
    const int t = threadIdx.x;
    const int ks = blockIdx.y, k0 = ks * 32, cb = blockIdx.x;
    gemv_core<8, 4096>(headw, 4096, cb * 256, k0, xsl, accbuf, hdp, cb, ks, [&]() {
        if (t < 128) {
            const int row = t >> 2, b = t & 3;
            const int gr = k0 + row;
            float hn = hB[b * 1024 + gr];
            #pragma unroll 16
            for (int c = 0; c < 48; c++) hn += dwp[(size_t)(c * 4 + b) * 1024 + gr];
            sred[t] = hn * hn;
            const float x = hn * normw[gr];
            xsl[row * 4 + b] = x;
            if (cb == 0) xfu[b * 1024 + gr] = x;
        }
        __syncthreads();
        if (cb == 0 && t < 4) {
            float s = 0.f;
            #pragma unroll
            for (int r = 0; r < 32; r++) s += sred[r * 4 + t];
            ssqpF[ks * 4 + t] = s;
        }
    });
}

// ---------------- logits reduce + deferred rms_f + past: grid 16 ----------------
__global__ __launch_bounds__(256) void k_logits(
    const float* __restrict__ hdp, const float* __restrict__ ssqpF,
    const float* __restrict__ xfu,
    float* __restrict__ logits, float* __restrict__ past)
{
    __shared__ float rsh;
    const int t = threadIdx.x, bid = blockIdx.x;
    const int b = bid >> 2;
    if (t == 0) {
        float s = 0.f;
        #pragma unroll
        for (int i = 0; i < 32; i++) s += ssqpF[i * 4 + b];
        rsh = rsqrtf(s * (1.f / 1024.f) + EPS_);
    }
    __syncthreads();
    const float rf = rsh;
    const int t4 = bid * 256 + t;       // 0..4095 float4s; b = t4>>10
    const int n4 = t4 & 1023;
    float4 s = {0.f, 0.f, 0.f, 0.f};
    #pragma unroll
    for (int c = 0; c < 32; c++) {
        float4 v = *(const float4*)(hdp + ((size_t)c * 4 + b) * 4096 + n4 * 4);
        s.x += v.x; s.y += v.y; s.z += v.z; s.w += v.w;
    }
    s.x *= rf; s.y *= rf; s.z *= rf; s.w *= rf;
    *(float4*)(logits + (size_t)t4 * 4) = s;
    if (t < 64) {
        const int p = bid * 64 + t;
        const int i4 = p & 255;
        float4 x = *(const float4*)(xfu + b * 1024 + i4 * 4);
        x.x *= rf; x.y *= rf; x.z *= rf; x.w *= rf;
        *(float4*)(past + (size_t)p * 4) = x;
    }
}

extern "C" void kernel_launch(void* const* d_in, const int* in_sizes, int n_in,
                              void* d_out, int out_size, void* d_ws, size_t ws_size,
                              hipStream_t stream)
{
    const int*   cb0   = (const int*)d_in[0];
    const int*   cb1   = (const int*)d_in[1];
    const float* trail = (const float*)d_in[2];
    const float* kvin  = (const float*)d_in[3];
    const int*   pos   = (const int*)d_in[4];
    const float* cb0e  = (const float*)d_in[5];
    const float* cpe   = (const float*)d_in[6];
    const float* Wq    = (const float*)d_in[7];
    const float* Wk    = (const float*)d_in[8];
    const float* Wv    = (const float*)d_in[9];
    const float* Wo    = (const float*)d_in[10];
    const float* qnw   = (const float*)d_in[11];
    const float* knw   = (const float*)d_in[12];
    const float* ln1   = (const float*)d_in[13];
    const float* ln2   = (const float*)d_in[14];
    const float* Wg    = (const float*)d_in[15];
    const float* Wu    = (const float*)d_in[16];
    const float* Wd    = (const float*)d_in[17];
    const float* normw = (const float*)d_in[18];
    const float* headw = (const float*)d_in[19];

    float* out    = (float*)d_out;
    float* logits = out;
    float* kvout  = out + 16384;
    float* past   = out + 16384 + (size_t)2 * L_ * B_ * KVH_ * (S_ + 1) * HD_;
    float* ws = (float*)d_ws;

    float* hA    = ws + WS_HA;
    float* hB    = ws + WS_HB;
    float* xfu   = ws + WS_XFU;
    float* ssqp1 = ws + WS_SSQ1;
    float* ssqp2 = ws + WS_SSQ2;
    float* ssqpF = ws + WS_SSQF;
    float* qkvp  = ws + WS_QKVP;
    float* atto  = ws + WS_ATTO;
    float* atml  = ws + WS_ATML;
    float* gup   = ws + WS_GUP;
    float* dwp   = ws + WS_DWP;
    float* hdp   = ws + WS_HDP;

    const size_t IN_PLANE  = (size_t)B_ * KVH_ * S_ * HD_;
    const size_t OUT_PLANE = (size_t)B_ * KVH_ * (S_ + 1) * HD_;

    for (int l = 0; l < L_; l++) {
        if (l == 0)
            k_qkv<true><<<dim3(8, 32), 256, 0, stream>>>(
                hB, dwp, cb0, cb1, trail, cb0e, cpe, ln1 + (size_t)l * H_,
                Wq + (size_t)l * H_ * 1024, Wk + (size_t)l * H_ * 512,
                Wv + (size_t)l * H_ * 512, hA, ssqp1, qkvp);
        else
            k_qkv<false><<<dim3(8, 32), 256, 0, stream>>>(
                hB, dwp, cb0, cb1, trail, cb0e, cpe, ln1 + (size_t)l * H_,
                Wq + (size_t)l * H_ * 1024, Wk + (size_t)l * H_ * 512,
                Wv + (size_t)l * H_ * 512, hA, ssqp1, qkvp);
        k_attn<<<dim3(16, 16), 256, 0, stream>>>(
            qkvp, ssqp1, qnw + (size_t)l * HD_, knw + (size_t)l * HD_,
            kvin + (size_t)(2 * l) * IN_PLANE, kvin + (size_t)(2 * l + 1) * IN_PLANE,
            kvout + (size_t)(2 * l) * OUT_PLANE, kvout + (size_t)(2 * l + 1) * OUT_PLANE,
            pos, atto, atml);
        k_gateup<<<dim3(8, 32), 256, 0, stream>>>(
            hA, atto, atml, Wo + (size_t)l * 1024 * H_, ln2 + (size_t)l * H_,
            Wg + (size_t)l * H_ * I_, Wu + (size_t)l * H_ * I_, hB, ssqp2, gup);
        k_down<<<dim3(4, 48), 256, 0, stream>>>(
            gup, ssqp2, Wd + (size_t)l * I_ * H_, dwp);
    }
    k_head<<<dim3(16, 32), 256, 0, stream>>>(hB, dwp, normw, headw, xfu, ssqpF, hdp);
    k_logits<<<16, 256, 0, stream>>>(hdp, ssqpF, xfu, logits, past);
}

// Round 15
// 1163.870 us; speedup vs baseline: 1.1121x; 1.1121x over previous
//
#include <hip/hip_runtime.h>
#include <math.h>

#define L_  28
#define H_  1024
#define NH_ 8
#define KVH_ 4
#define HD_ 128
#define I_  3072
#define VC_ 4096
#define B_  4
#define S_  512
#define EPS_ 1e-6f

// ---- workspace layout (float offsets) ----
#define WS_HA    0            // [4][1024] h after attn-input fold (h3)
#define WS_HB    4096         // [4][1024] h after mlp-input fold (h4)
#define WS_XFU   8192         // [4][1024] unscaled final-normed x
#define WS_SSQ1  12288        // [32 ks][4 b] ssq partials of h3
#define WS_SSQ2  12416        // [32 ks][4 b] ssq partials of h4
#define WS_SSQF  12544        // [32 ks][4 b] ssq partials of h_final
#define WS_QKVP  12672        // [32][4][2048]
#define WS_ATTO  274816       // [16 bg][2 r][16 c][128]
#define WS_ATML  340352       // [16 bg][2 r][16 c][2]
#define WS_OPP   341376       // [32][4][1024]
#define WS_GUP   472448       // [32][4][6144]
#define WS_DWP   1258880      // [48][4][1024]
#define WS_HDP   1455488      // [32][4][4096]

typedef float v4f __attribute__((ext_vector_type(4)));

__device__ __forceinline__ float4 ntld4(const float* p) {
    v4f r = __builtin_nontemporal_load(reinterpret_cast<const v4f*>(p));
    return make_float4(r.x, r.y, r.z, r.w);
}
__device__ __forceinline__ void ntst4(float* p, float4 v) {
    v4f r = {v.x, v.y, v.z, v.w};
    __builtin_nontemporal_store(r, reinterpret_cast<v4f*>(p));
}

__device__ __forceinline__ float wave_reduce_sum(float v) {
    #pragma unroll
    for (int off = 32; off; off >>= 1) v += __shfl_down(v, off);
    return v;
}
__device__ __forceinline__ float wave_reduce_max(float v) {
    #pragma unroll
    for (int off = 32; off; off >>= 1) v = fmaxf(v, __shfl_down(v, off));
    return v;
}

// ---------------- bulk KV-cache copy: all 56 planes, s=0..511 (dependency-free) ----------------
// in: [56][B*KVH=16... flattened slab][512*128]; out slabs stride 513*128.
// 14,680,064 float4s = 2048 blocks x 256 thr x 28 iters.
__global__ __launch_bounds__(256) void k_kvcopy(
    const float* __restrict__ kvin, float* __restrict__ kvout)
{
    const int idx = blockIdx.x * 256 + threadIdx.x;     // 0..524287
    #pragma unroll 4
    for (int i = 0; i < 28; i++) {
        const size_t f = (size_t)i * 524288 + idx;      // float4 index
        const size_t slab = f >> 14;                     // / 16384 (512*128/4)
        const size_t w = f & 16383;
        float4 v = ntld4(kvin + (slab * 16384 + w) * 4);
        ntst4(kvout + (slab * 16416 + w) * 4, v);        // 513*128/4 = 16416
    }
}

// ---------------- GEMV core: NT weight preload -> prologue -> FMA -> LDS reduce -> store ----------------
template<int RPW, int NTOT, typename F>
__device__ __forceinline__ void gemv_core(
    const float* __restrict__ W, int ldw, int wcol0, int k0,
    float* __restrict__ xsl, float4* __restrict__ accbuf,
    float* __restrict__ pp, int colblk, int ks, F&& prologue)
{
    const int t = threadIdx.x;
    const int wv = t >> 6, lane = t & 63;
    const float* Wp = W + (size_t)(k0 + wv * RPW) * ldw + wcol0 + lane * 4;
    float4 wreg[RPW];
    #pragma unroll
    for (int i = 0; i < RPW; i++) wreg[i] = ntld4(Wp + (size_t)i * ldw);
    prologue();   // fills xsl; ends with __syncthreads()
    const float4* xs4 = (const float4*)xsl;
    float4 a0 = {0,0,0,0}, a1 = {0,0,0,0}, a2 = {0,0,0,0}, a3 = {0,0,0,0};
    #pragma unroll
    for (int i = 0; i < RPW; i++) {
        float4 w4 = wreg[i];
        float4 xb = xs4[wv * RPW + i];
        a0.x += w4.x * xb.x; a0.y += w4.y * xb.x; a0.z += w4.z * xb.x; a0.w += w4.w * xb.x;
        a1.x += w4.x * xb.y; a1.y += w4.y * xb.y; a1.z += w4.z * xb.y; a1.w += w4.w * xb.y;
        a2.x += w4.x * xb.z; a2.y += w4.y * xb.z; a2.z += w4.z * xb.z; a2.w += w4.w * xb.z;
        a3.x += w4.x * xb.w; a3.y += w4.y * xb.w; a3.z += w4.z * xb.w; a3.w += w4.w * xb.w;
    }
    accbuf[(wv * 64 + lane) * 4 + 0] = a0;
    accbuf[(wv * 64 + lane) * 4 + 1] = a1;
    accbuf[(wv * 64 + lane) * 4 + 2] = a2;
    accbuf[(wv * 64 + lane) * 4 + 3] = a3;
    __syncthreads();
    const int l2 = t >> 2, b2 = t & 3;
    float4 s0 = accbuf[(0 * 64 + l2) * 4 + b2];
    float4 s1 = accbuf[(1 * 64 + l2) * 4 + b2];
    float4 s2 = accbuf[(2 * 64 + l2) * 4 + b2];
    float4 s3 = accbuf[(3 * 64 + l2) * 4 + b2];
    float4 s;
    s.x = s0.x + s1.x + s2.x + s3.x;
    s.y = s0.y + s1.y + s2.y + s3.y;
    s.z = s0.z + s1.z + s2.z + s3.z;
    s.w = s0.w + s1.w + s2.w + s3.w;
    *(float4*)(pp + ((size_t)ks * 4 + b2) * NTOT + colblk * 256 + l2 * 4) = s;
}

// ---------------- qkv (fused embed for l==0; fold+norm prologue): grid (8, 32) ----------------
template<bool FIRST>
__global__ __launch_bounds__(256) void k_qkv(
    const float* __restrict__ hPrev, const float* __restrict__ dwp,
    const int* __restrict__ cb0, const int* __restrict__ cb1,
    const float* __restrict__ trail, const float* __restrict__ cb0e,
    const float* __restrict__ cpe,
    const float* __restrict__ ln1,
    const float* __restrict__ Wq, const float* __restrict__ Wk,
    const float* __restrict__ Wv,
    float* __restrict__ hA, float* __restrict__ ssqp1, float* __restrict__ qkvp)
{
    __shared__ float xsl[128];
    __shared__ float4 accbuf[1024];
    __shared__ float sred[128];
    const int t = threadIdx.x;
    const int ks = blockIdx.y, k0 = ks * 32, cb = blockIdx.x;
    const float* W; int ldw, wcol0;
    if (cb < 4)      { W = Wq; ldw = 1024; wcol0 = cb * 256; }
    else if (cb < 6) { W = Wk; ldw = 512;  wcol0 = (cb - 4) * 256; }
    else             { W = Wv; ldw = 512;  wcol0 = (cb - 6) * 256; }
    gemv_core<8, 2048>(W, ldw, wcol0, k0, xsl, accbuf, qkvp, cb, ks, [&]() {
        if (t < 128) {
            const int row = t >> 2, b = t & 3;
            const int gr = k0 + row;
            float hn;
            if (FIRST) {
                hn = cb0e[(size_t)cb0[b] * 1024 + gr] + trail[b * 1024 + gr];
                #pragma unroll
                for (int j = 0; j < 15; j++)
                    hn += cpe[((size_t)j * 4096 + cb1[b * 15 + j]) * 1024 + gr];
            } else {
                hn = hPrev[b * 1024 + gr];
                #pragma unroll 16
                for (int c = 0; c < 48; c++) hn += dwp[(size_t)(c * 4 + b) * 1024 + gr];
            }
            sred[t] = hn * hn;
            xsl[row * 4 + b] = hn * ln1[gr];
            if (cb == 0) hA[b * 1024 + gr] = hn;
        }
        __syncthreads();
        if (cb == 0 && t < 4) {
            float s = 0.f;
            #pragma unroll
            for (int r = 0; r < 32; r++) s += sred[r * 4 + t];
            ssqp1[ks * 4 + t] = s;
        }
    });
}

// ---------------- attention flash chunk (copy REMOVED; only s=512 write): grid (16 bg, 16 c) ----------------
__global__ __launch_bounds__(256) void k_attn(
    const float* __restrict__ qkvp, const float* __restrict__ ssqp1,
    const float* __restrict__ qnw, const float* __restrict__ knw,
    const float* __restrict__ kin, const float* __restrict__ vin,
    float* __restrict__ kout, float* __restrict__ vout,
    const int* __restrict__ pos,
    float* __restrict__ opart, float* __restrict__ mlpart)
{
    __shared__ float Kl[33][129];
    __shared__ float Vl[33][129];
    __shared__ float ql[2][128];
    __shared__ float sc[2][36];
    __shared__ float red[8];
    __shared__ float rms1sh;

    const int t = threadIdx.x;
    const int bg = blockIdx.x, b = bg >> 2, g = bg & 3;
    const int c = blockIdx.y;           // 0..15
    const int lane = t & 63;
    const int r = t >> 7, d = t & 127;
    const float scale = 0.088388347648318447f;  // 1/sqrt(128)

    if (c == 15 && t == 0) {
        float s = 0.f;
        #pragma unroll
        for (int i = 0; i < 32; i++) s += ssqp1[i * 4 + b];
        rms1sh = rsqrtf(s * (1.f / 1024.f) + EPS_);
    }

    const float posf = (float)pos[b];
    const int j = d & 63;
    const float invf = exp2f(-(float)j * 0.31143075889569021f);  // 1e6^(-j/64)
    const float ang = posf * invf;
    const float cs = cosf(ang), sn = sinf(ang);
    const int pd = (d < 64) ? d + 64 : d - 64;

    // q: reduce 32 split-K chunks (UNSCALED -- head-norm is scale-invariant)
    float qraw = 0.f;
    {
        const int n = (2 * g + r) * 128 + d;
        #pragma unroll
        for (int cc = 0; cc < 32; cc++) qraw += qkvp[((size_t)cc * 4 + b) * 2048 + n];
    }
    ql[r][d] = qraw;
    float ssq = wave_reduce_sum(qraw * qraw);
    if (lane == 0) red[t >> 6] = ssq;
    __syncthreads();  // (A)
    const float rms_q = rsqrtf((red[r * 2] + red[r * 2 + 1]) * (1.f / 128.f) + EPS_);
    float qv = qraw * rms_q * qnw[d];
    float qp = ql[r][pd] * rms_q * qnw[pd];
    float qro = qv * cs + ((d < 64) ? -qp : qp) * sn;

    // new k/v: only chunk 15
    float kvraw = 0.f;
    if (c == 15) {
        const int base = (t < 128) ? (1024 + g * 128 + d) : (1536 + g * 128 + d);
        #pragma unroll
        for (int cc = 0; cc < 32; cc++) kvraw += qkvp[((size_t)cc * 4 + b) * 2048 + base];
    }
    float kss = wave_reduce_sum((t < 128) ? kvraw * kvraw : 0.f);
    __syncthreads();  // (B)
    ql[r][d] = qro;
    if (lane == 0 && t < 128) red[t >> 6] = kss;
    if (c == 15) { if (t < 128) Kl[32][d] = kvraw; else Vl[32][d] = kvraw; }
    __syncthreads();  // (C)
    float newkv = 0.f;
    if (c == 15) {
        if (t < 128) {
            const float rms_k = rsqrtf((red[0] + red[1]) * (1.f / 128.f) + EPS_);
            float kv_ = Kl[32][d] * rms_k * knw[d];
            float kp  = Kl[32][pd] * rms_k * knw[pd];
            newkv = kv_ * cs + ((d < 64) ? -kp : kp) * sn;
        } else {
            newkv = Vl[32][d] * rms1sh;      // deferred rms1 on V
        }
    }
    __syncthreads();  // (D)
    const size_t out_bg = (size_t)bg * (513 * 128);
    if (c == 15) {
        if (t < 128) { Kl[32][d] = newkv; kout[out_bg + 512 * 128 + d] = newkv; }
        else         { Vl[32][d] = newkv; vout[out_bg + 512 * 128 + d] = newkv; }
    }

    // KV tile (32 keys) load into LDS (NT float4) -- bulk copy handled by k_kvcopy
    const size_t in_bg = (size_t)bg * (512 * 128);
    const int s0 = c * 32;
    #pragma unroll
    for (int i = 0; i < 4; i++) {
        int f4 = i * 256 + t;
        int row = f4 >> 5, d0 = (f4 & 31) * 4;
        float4 k4 = ntld4(kin + in_bg + (size_t)(s0 + row) * 128 + d0);
        float4 v4 = ntld4(vin + in_bg + (size_t)(s0 + row) * 128 + d0);
        Kl[row][d0] = k4.x; Kl[row][d0 + 1] = k4.y; Kl[row][d0 + 2] = k4.z; Kl[row][d0 + 3] = k4.w;
        Vl[row][d0] = v4.x; Vl[row][d0 + 1] = v4.y; Vl[row][d0 + 2] = v4.z; Vl[row][d0 + 3] = v4.w;
    }
    __syncthreads();  // (E)

    // scores
    const int nk = (c == 15) ? 33 : 32;
    const int si = d;
    float sv = -1e30f;
    if (si < nk) {
        float a = 0.f;
        #pragma unroll 8
        for (int dd = 0; dd < 128; dd++) a += ql[r][dd] * Kl[si][dd];
        sv = a * scale;
    }
    float mv = wave_reduce_max(sv);
    if (lane == 0) red[t >> 6] = mv;
    __syncthreads();
    const float m = fmaxf(red[r * 2], red[r * 2 + 1]);
    float p = (si < nk) ? expf(sv - m) : 0.f;
    if (si < nk) sc[r][si] = p;
    float lsum = wave_reduce_sum(p);
    __syncthreads();
    if (lane == 0) red[t >> 6] = lsum;
    __syncthreads();
    const float lr = red[r * 2] + red[r * 2 + 1];
    if (d == 0) {
        mlpart[(size_t)((bg * 2 + r) * 16 + c) * 2 + 0] = m;
        mlpart[(size_t)((bg * 2 + r) * 16 + c) * 2 + 1] = lr;
    }
    float o = 0.f;
    for (int s2 = 0; s2 < nk; s2++) o += sc[r][s2] * Vl[s2][d];
    opart[(size_t)((bg * 2 + r) * 16 + c) * 128 + d] = o;
}

// ---------------- o-proj GEMV (flash-combine prologue): grid (4, 32) ----------------
__global__ __launch_bounds__(256) void k_oproj(
    const float* __restrict__ atto, const float* __restrict__ atml,
    const float* __restrict__ Wo_l, float* __restrict__ opp)
{
    __shared__ float xsl[128];
    __shared__ float4 accbuf[1024];
    const int t = threadIdx.x;
    const int ks = blockIdx.y, k0 = ks * 32, cb = blockIdx.x;
    gemv_core<8, 1024>(Wo_l, 1024, cb * 256, k0, xsl, accbuf, opp, cb, ks, [&]() {
        if (t < 128) {
            const int kk = t & 31, b = t >> 5;
            const int nrow = k0 + kk;
            const int head = nrow >> 7, dh = nrow & 127;
            const int g = head >> 1, rr = head & 1;
            const size_t base = (size_t)((b * 4 + g) * 2 + rr) * 16;
            float mc[16], lc[16], M = -1e30f;
            #pragma unroll
            for (int cc = 0; cc < 16; cc++) {
                mc[cc] = atml[(base + cc) * 2];
                lc[cc] = atml[(base + cc) * 2 + 1];
                M = fmaxf(M, mc[cc]);
            }
            float Ls = 0.f, o = 0.f;
            #pragma unroll
            for (int cc = 0; cc < 16; cc++) {
                float wch = expf(mc[cc] - M);
                Ls += lc[cc] * wch;
                o += atto[(base + cc) * 128 + dh] * wch;
            }
            xsl[kk * 4 + b] = o / Ls;
        }
        __syncthreads();
    });
}

// ---------------- gate/up: grid (8, 32) = 256 blocks; 3 column-units/block, single fold ----------------
__global__ __launch_bounds__(256) void k_gateup(
    const float* __restrict__ hA, const float* __restrict__ opp,
    const float* __restrict__ ln2,
    const float* __restrict__ Wg_l, const float* __restrict__ Wu_l,
    float* __restrict__ hB, float* __restrict__ ssqp2, float* __restrict__ gup)
{
    __shared__ float xsl[128];
    __shared__ float4 accbuf[1024];
    __shared__ float sred[128];
    const int t = threadIdx.x;
    const int ks = blockIdx.y, k0 = ks * 32, bx = blockIdx.x;
    const int wv = t >> 6, lane = t & 63;
    const int u0 = bx * 3;

    // preload unit 0 weights (NT)
    float4 wA[8], wB[8];
    {
        const float* Wp = ((u0 < 12) ? (Wg_l + u0 * 256) : (Wu_l + (u0 - 12) * 256))
                          + (size_t)(k0 + wv * 8) * 3072 + lane * 4;
        #pragma unroll
        for (int i = 0; i < 8; i++) wA[i] = ntld4(Wp + (size_t)i * 3072);
    }

    // fold + ln2 prologue (ONCE for all 3 units)
    if (t < 128) {
        const int row = t >> 2, b = t & 3;
        const int gr = k0 + row;
        float hn = hA[b * 1024 + gr];
        #pragma unroll 16
        for (int c = 0; c < 32; c++) hn += opp[(size_t)(c * 4 + b) * 1024 + gr];
        sred[t] = hn * hn;
        xsl[row * 4 + b] = hn * ln2[gr];
        if (bx == 0) hB[b * 1024 + gr] = hn;
    }
    __syncthreads();
    if (bx == 0 && t < 4) {
        float s = 0.f;
        #pragma unroll
        for (int r = 0; r < 32; r++) s += sred[r * 4 + t];
        ssqp2[ks * 4 + t] = s;
    }

    const float4* xs4 = (const float4*)xsl;
    #pragma unroll
    for (int j = 0; j < 3; j++) {
        const int u = u0 + j;
        if (j < 2) {   // prefetch next unit before the LDS reduce
            const int un = u0 + j + 1;
            const float* Wpn = ((un < 12) ? (Wg_l + un * 256) : (Wu_l + (un - 12) * 256))
                               + (size_t)(k0 + wv * 8) * 3072 + lane * 4;
            float4* wn = (j == 0) ? wB : wA;
            #pragma unroll
            for (int i = 0; i < 8; i++) wn[i] = ntld4(Wpn + (size_t)i * 3072);
        }
        const float4* wc = (j == 1) ? wB : wA;
        float4 a0 = {0,0,0,0}, a1 = {0,0,0,0}, a2 = {0,0,0,0}, a3 = {0,0,0,0};
        #pragma unroll
        for (int i = 0; i < 8; i++) {
            float4 w4 = wc[i];
            float4 xb = xs4[wv * 8 + i];
            a0.x += w4.x * xb.x; a0.y += w4.y * xb.x; a0.z += w4.z * xb.x; a0.w += w4.w * xb.x;
            a1.x += w4.x * xb.y; a1.y += w4.y * xb.y; a1.z += w4.z * xb.y; a1.w += w4.w * xb.y;
            a2.x += w4.x * xb.z; a2.y += w4.y * xb.z; a2.z += w4.z * xb.z; a2.w += w4.w * xb.z;
            a3.x += w4.x * xb.w; a3.y += w4.y * xb.w; a3.z += w4.z * xb.w; a3.w += w4.w * xb.w;
        }
        accbuf[(wv * 64 + lane) * 4 + 0] = a0;
        accbuf[(wv * 64 + lane) * 4 + 1] = a1;
        accbuf[(wv * 64 + lane) * 4 + 2] = a2;
        accbuf[(wv * 64 + lane) * 4 + 3] = a3;
        __syncthreads();
        const int l2 = t >> 2, b2 = t & 3;
        float4 s0 = accbuf[(0 * 64 + l2) * 4 + b2];
        float4 s1 = accbuf[(1 * 64 + l2) * 4 + b2];
        float4 s2 = accbuf[(2 * 64 + l2) * 4 + b2];
        float4 s3 = accbuf[(3 * 64 + l2) * 4 + b2];
        float4 s;
        s.x = s0.x + s1.x + s2.x + s3.x;
        s.y = s0.y + s1.y + s2.y + s3.y;
        s.z = s0.z + s1.z + s2.z + s3.z;
        s.w = s0.w + s1.w + s2.w + s3.w;
        const int ucol0 = (u < 12) ? u * 256 : 3072 + (u - 12) * 256;
        *(float4*)(gup + ((size_t)ks * 4 + b2) * 6144 + ucol0 + l2 * 4) = s;
        __syncthreads();
    }
}

// ---------------- down: deferred rms2 before SiLU. grid (4, 48) ----------------
__global__ __launch_bounds__(256) void k_down(
    const float* __restrict__ gup, const float* __restrict__ ssqp2,
    const float* __restrict__ Wd_l, float* __restrict__ dwp)
{
    __shared__ float xsl[256];
    __shared__ float4 accbuf[1024];
    __shared__ float rmsb[4];
    const int t = threadIdx.x;
    const int ks = blockIdx.y, k0 = ks * 64, cb = blockIdx.x;
    gemv_core<16, 1024>(Wd_l, 1024, cb * 256, k0, xsl, accbuf, dwp, cb, ks, [&]() {
        if (t < 4) {
            float s = 0.f;
            #pragma unroll
            for (int i = 0; i < 32; i++) s += ssqp2[i * 4 + t];
            rmsb[t] = rsqrtf(s * (1.f / 1024.f) + EPS_);
        }
        __syncthreads();
        const int b = t >> 6, kk = t & 63;
        const float rm = rmsb[b];
        float gg = 0.f, uu = 0.f;
        #pragma unroll 8
        for (int cc = 0; cc < 32; cc++) {
            gg += gup[((size_t)cc * 4 + b) * 6144 + k0 + kk];
            uu += gup[((size_t)cc * 4 + b) * 6144 + 3072 + k0 + kk];
        }
        gg *= rm; uu *= rm;
        xsl[kk * 4 + b] = gg / (1.f + expf(-gg)) * uu;
        __syncthreads();
    });
}

// ---------------- head: fold h_final rows; UNSCALED x = h*normw. grid (16, 32) ----------------
__global__ __launch_bounds__(256) void k_head(
    const float* __restrict__ hB, const float* __restrict__ dwp,
    const float* __restrict__ normw, const float* __restrict__ headw,
    float* __restrict__ xfu, float* __restrict__ ssqpF, float* __restrict__ hdp)
{
    __shared__ float xsl[128];
    __shared__ float4 accbuf[1024];
    __shared__ float sred[128];
    const int t = threadIdx.x;
    const int ks = blockIdx.y, k0 = ks * 32, cb = blockIdx.x;
    gemv_core<8, 4096>(headw, 4096, cb * 256, k0, xsl, accbuf, hdp, cb, ks, [&]() {
        if (t < 128) {
            const int row = t >> 2, b = t & 3;
            const int gr = k0 + row;
            float hn = hB[b * 1024 + gr];
            #pragma unroll 16
            for (int c = 0; c < 48; c++) hn += dwp[(size_t)(c * 4 + b) * 1024 + gr];
            sred[t] = hn * hn;
            const float x = hn * normw[gr];
            xsl[row * 4 + b] = x;
            if (cb == 0) xfu[b * 1024 + gr] = x;
        }
        __syncthreads();
        if (cb == 0 && t < 4) {
            float s = 0.f;
            #pragma unroll
            for (int r = 0; r < 32; r++) s += sred[r * 4 + t];
            ssqpF[ks * 4 + t] = s;
        }
    });
}

// ---------------- logits reduce + deferred rms_f + past: grid 16 ----------------
__global__ __launch_bounds__(256) void k_logits(
    const float* __restrict__ hdp, const float* __restrict__ ssqpF,
    const float* __restrict__ xfu,
    float* __restrict__ logits, float* __restrict__ past)
{
    __shared__ float rsh;
    const int t = threadIdx.x, bid = blockIdx.x;
    const int b = bid >> 2;
    if (t == 0) {
        float s = 0.f;
        #pragma unroll
        for (int i = 0; i < 32; i++) s += ssqpF[i * 4 + b];
        rsh = rsqrtf(s * (1.f / 1024.f) + EPS_);
    }
    __syncthreads();
    const float rf = rsh;
    const int t4 = bid * 256 + t;       // 0..4095 float4s; b = t4>>10
    const int n4 = t4 & 1023;
    float4 s = {0.f, 0.f, 0.f, 0.f};
    #pragma unroll
    for (int c = 0; c < 32; c++) {
        float4 v = *(const float4*)(hdp + ((size_t)c * 4 + b) * 4096 + n4 * 4);
        s.x += v.x; s.y += v.y; s.z += v.z; s.w += v.w;
    }
    s.x *= rf; s.y *= rf; s.z *= rf; s.w *= rf;
    *(float4*)(logits + (size_t)t4 * 4) = s;
    if (t < 64) {
        const int p = bid * 64 + t;
        const int i4 = p & 255;
        float4 x = *(const float4*)(xfu + b * 1024 + i4 * 4);
        x.x *= rf; x.y *= rf; x.z *= rf; x.w *= rf;
        *(float4*)(past + (size_t)p * 4) = x;
    }
}

extern "C" void kernel_launch(void* const* d_in, const int* in_sizes, int n_in,
                              void* d_out, int out_size, void* d_ws, size_t ws_size,
                              hipStream_t stream)
{
    const int*   cb0   = (const int*)d_in[0];
    const int*   cb1   = (const int*)d_in[1];
    const float* trail = (const float*)d_in[2];
    const float* kvin  = (const float*)d_in[3];
    const int*   pos   = (const int*)d_in[4];
    const float* cb0e  = (const float*)d_in[5];
    const float* cpe   = (const float*)d_in[6];
    const float* Wq    = (const float*)d_in[7];
    const float* Wk    = (const float*)d_in[8];
    const float* Wv    = (const float*)d_in[9];
    const float* Wo    = (const float*)d_in[10];
    const float* qnw   = (const float*)d_in[11];
    const float* knw   = (const float*)d_in[12];
    const float* ln1   = (const float*)d_in[13];
    const float* ln2   = (const float*)d_in[14];
    const float* Wg    = (const float*)d_in[15];
    const float* Wu    = (const float*)d_in[16];
    const float* Wd    = (const float*)d_in[17];
    const float* normw = (const float*)d_in[18];
    const float* headw = (const float*)d_in[19];

    float* out    = (float*)d_out;
    float* logits = out;
    float* kvout  = out + 16384;
    float* past   = out + 16384 + (size_t)2 * L_ * B_ * KVH_ * (S_ + 1) * HD_;
    float* ws = (float*)d_ws;

    float* hA    = ws + WS_HA;
    float* hB    = ws + WS_HB;
    float* xfu   = ws + WS_XFU;
    float* ssqp1 = ws + WS_SSQ1;
    float* ssqp2 = ws + WS_SSQ2;
    float* ssqpF = ws + WS_SSQF;
    float* qkvp  = ws + WS_QKVP;
    float* atto  = ws + WS_ATTO;
    float* atml  = ws + WS_ATML;
    float* opp   = ws + WS_OPP;
    float* gup   = ws + WS_GUP;
    float* dwp   = ws + WS_DWP;
    float* hdp   = ws + WS_HDP;

    const size_t IN_PLANE  = (size_t)B_ * KVH_ * S_ * HD_;
    const size_t OUT_PLANE = (size_t)B_ * KVH_ * (S_ + 1) * HD_;

    k_kvcopy<<<2048, 256, 0, stream>>>(kvin, kvout);

    for (int l = 0; l < L_; l++) {
        if (l == 0)
            k_qkv<true><<<dim3(8, 32), 256, 0, stream>>>(
                hB, dwp, cb0, cb1, trail, cb0e, cpe, ln1 + (size_t)l * H_,
                Wq + (size_t)l * H_ * 1024, Wk + (size_t)l * H_ * 512,
                Wv + (size_t)l * H_ * 512, hA, ssqp1, qkvp);
        else
            k_qkv<false><<<dim3(8, 32), 256, 0, stream>>>(
                hB, dwp, cb0, cb1, trail, cb0e, cpe, ln1 + (size_t)l * H_,
                Wq + (size_t)l * H_ * 1024, Wk + (size_t)l * H_ * 512,
                Wv + (size_t)l * H_ * 512, hA, ssqp1, qkvp);
        k_attn<<<dim3(16, 16), 256, 0, stream>>>(
            qkvp, ssqp1, qnw + (size_t)l * HD_, knw + (size_t)l * HD_,
            kvin + (size_t)(2 * l) * IN_PLANE, kvin + (size_t)(2 * l + 1) * IN_PLANE,
            kvout + (size_t)(2 * l) * OUT_PLANE, kvout + (size_t)(2 * l + 1) * OUT_PLANE,
            pos, atto, atml);
        k_oproj<<<dim3(4, 32), 256, 0, stream>>>(
            atto, atml, Wo + (size_t)l * 1024 * H_, opp);
        k_gateup<<<dim3(8, 32), 256, 0, stream>>>(
            hA, opp, ln2 + (size_t)l * H_,
            Wg + (size_t)l * H_ * I_, Wu + (size_t)l * H_ * I_, hB, ssqp2, gup);
        k_down<<<dim3(4, 48), 256, 0, stream>>>(
            gup, ssqp2, Wd + (size_t)l * I_ * H_, dwp);
    }
    k_head<<<dim3(16, 32), 256, 0, stream>>>(hB, dwp, normw, headw, xfu, ssqpF, hdp);
    k_logits<<<16, 256, 0, stream>>>(hdp, ssqpF, xfu, logits, past);
}

// Round 16
// 1091.635 us; speedup vs baseline: 1.1857x; 1.0662x over previous
//
#include <hip/hip_runtime.h>
#include <math.h>

#define L_  28
#define H_  1024
#define NH_ 8
#define KVH_ 4
#define HD_ 128
#define I_  3072
#define VC_ 4096
#define B_  4
#define S_  512
#define EPS_ 1e-6f

// ---- workspace layout (float offsets) ----
#define WS_HA    0            // [4][1024] h after attn-input fold (h3)
#define WS_HB    4096         // [4][1024] h after mlp-input fold (h4)
#define WS_XFU   8192         // [4][1024] unscaled final-normed x
#define WS_SSQ1  12288        // [32 ks][4 b] ssq partials of h3
#define WS_SSQ2  12416        // [32 ks][4 b] ssq partials of h4
#define WS_SSQF  12544        // [32 ks][4 b] ssq partials of h_final
#define WS_QKVP  12672        // [32][4][2048]
#define WS_ATTO  274816       // [16 bg][2 r][16 c][128]
#define WS_ATML  340352       // [16 bg][2 r][16 c][2]
#define WS_OPP   341376       // [32][4][1024]
#define WS_GUP   472448       // [32][4][6144]
#define WS_DWP   1258880      // [48][4][1024]
#define WS_HDP   1455488      // [32][4][4096]

typedef float v4f __attribute__((ext_vector_type(4)));

__device__ __forceinline__ float4 ntld4(const float* p) {
    v4f r = __builtin_nontemporal_load(reinterpret_cast<const v4f*>(p));
    return make_float4(r.x, r.y, r.z, r.w);
}
__device__ __forceinline__ void ntst4(float* p, float4 v) {
    v4f r = {v.x, v.y, v.z, v.w};
    __builtin_nontemporal_store(r, reinterpret_cast<v4f*>(p));
}

__device__ __forceinline__ float wave_reduce_sum(float v) {
    #pragma unroll
    for (int off = 32; off; off >>= 1) v += __shfl_down(v, off);
    return v;
}
__device__ __forceinline__ float wave_reduce_max(float v) {
    #pragma unroll
    for (int off = 32; off; off >>= 1) v = fmaxf(v, __shfl_down(v, off));
    return v;
}

// ---------------- GEMV core: NT weight preload -> prologue -> FMA -> LDS reduce -> store ----------------
template<int RPW, int NTOT, typename F>
__device__ __forceinline__ void gemv_core(
    const float* __restrict__ W, int ldw, int wcol0, int k0,
    float* __restrict__ xsl, float4* __restrict__ accbuf,
    float* __restrict__ pp, int colblk, int ks, F&& prologue)
{
    const int t = threadIdx.x;
    const int wv = t >> 6, lane = t & 63;
    const float* Wp = W + (size_t)(k0 + wv * RPW) * ldw + wcol0 + lane * 4;
    float4 wreg[RPW];
    #pragma unroll
    for (int i = 0; i < RPW; i++) wreg[i] = ntld4(Wp + (size_t)i * ldw);
    prologue();   // fills xsl; ends with __syncthreads()
    const float4* xs4 = (const float4*)xsl;
    float4 a0 = {0,0,0,0}, a1 = {0,0,0,0}, a2 = {0,0,0,0}, a3 = {0,0,0,0};
    #pragma unroll
    for (int i = 0; i < RPW; i++) {
        float4 w4 = wreg[i];
        float4 xb = xs4[wv * RPW + i];
        a0.x += w4.x * xb.x; a0.y += w4.y * xb.x; a0.z += w4.z * xb.x; a0.w += w4.w * xb.x;
        a1.x += w4.x * xb.y; a1.y += w4.y * xb.y; a1.z += w4.z * xb.y; a1.w += w4.w * xb.y;
        a2.x += w4.x * xb.z; a2.y += w4.y * xb.z; a2.z += w4.z * xb.z; a2.w += w4.w * xb.z;
        a3.x += w4.x * xb.w; a3.y += w4.y * xb.w; a3.z += w4.z * xb.w; a3.w += w4.w * xb.w;
    }
    accbuf[(wv * 64 + lane) * 4 + 0] = a0;
    accbuf[(wv * 64 + lane) * 4 + 1] = a1;
    accbuf[(wv * 64 + lane) * 4 + 2] = a2;
    accbuf[(wv * 64 + lane) * 4 + 3] = a3;
    __syncthreads();
    const int l2 = t >> 2, b2 = t & 3;
    float4 s0 = accbuf[(0 * 64 + l2) * 4 + b2];
    float4 s1 = accbuf[(1 * 64 + l2) * 4 + b2];
    float4 s2 = accbuf[(2 * 64 + l2) * 4 + b2];
    float4 s3 = accbuf[(3 * 64 + l2) * 4 + b2];
    float4 s;
    s.x = s0.x + s1.x + s2.x + s3.x;
    s.y = s0.y + s1.y + s2.y + s3.y;
    s.z = s0.z + s1.z + s2.z + s3.z;
    s.w = s0.w + s1.w + s2.w + s3.w;
    *(float4*)(pp + ((size_t)ks * 4 + b2) * NTOT + colblk * 256 + l2 * 4) = s;
}

// ---------------- qkv (fused embed for l==0; fold+norm prologue): grid (8, 32) ----------------
template<bool FIRST>
__global__ __launch_bounds__(256) void k_qkv(
    const float* __restrict__ hPrev, const float* __restrict__ dwp,
    const int* __restrict__ cb0, const int* __restrict__ cb1,
    const float* __restrict__ trail, const float* __restrict__ cb0e,
    const float* __restrict__ cpe,
    const float* __restrict__ ln1,
    const float* __restrict__ Wq, const float* __restrict__ Wk,
    const float* __restrict__ Wv,
    float* __restrict__ hA, float* __restrict__ ssqp1, float* __restrict__ qkvp)
{
    __shared__ float xsl[128];
    __shared__ float4 accbuf[1024];
    __shared__ float sred[128];
    const int t = threadIdx.x;
    const int ks = blockIdx.y, k0 = ks * 32, cb = blockIdx.x;
    const float* W; int ldw, wcol0;
    if (cb < 4)      { W = Wq; ldw = 1024; wcol0 = cb * 256; }
    else if (cb < 6) { W = Wk; ldw = 512;  wcol0 = (cb - 4) * 256; }
    else             { W = Wv; ldw = 512;  wcol0 = (cb - 6) * 256; }
    gemv_core<8, 2048>(W, ldw, wcol0, k0, xsl, accbuf, qkvp, cb, ks, [&]() {
        if (t < 128) {
            const int row = t >> 2, b = t & 3;
            const int gr = k0 + row;
            float hn;
            if (FIRST) {
                hn = cb0e[(size_t)cb0[b] * 1024 + gr] + trail[b * 1024 + gr];
                #pragma unroll
                for (int j = 0; j < 15; j++)
                    hn += cpe[((size_t)j * 4096 + cb1[b * 15 + j]) * 1024 + gr];
            } else {
                hn = hPrev[b * 1024 + gr];
                #pragma unroll 16
                for (int c = 0; c < 48; c++) hn += dwp[(size_t)(c * 4 + b) * 1024 + gr];
            }
            sred[t] = hn * hn;
            xsl[row * 4 + b] = hn * ln1[gr];
            if (cb == 0) hA[b * 1024 + gr] = hn;
        }
        __syncthreads();
        if (cb == 0 && t < 4) {
            float s = 0.f;
            #pragma unroll
            for (int r = 0; r < 32; r++) s += sred[r * 4 + t];
            ssqp1[ks * 4 + t] = s;
        }
    });
}

// ---------------- attention flash chunk (fused KV-cache copy): grid (16 bg, 16 c), block 256 ----------------
__global__ __launch_bounds__(256) void k_attn(
    const float* __restrict__ qkvp, const float* __restrict__ ssqp1,
    const float* __restrict__ qnw, const float* __restrict__ knw,
    const float* __restrict__ kin, const float* __restrict__ vin,
    float* __restrict__ kout, float* __restrict__ vout,
    const int* __restrict__ pos,
    float* __restrict__ opart, float* __restrict__ mlpart)
{
    __shared__ float Kl[33][129];
    __shared__ float Vl[33][129];
    __shared__ float ql[2][128];
    __shared__ float sc[2][36];
    __shared__ float red[8];
    __shared__ float rms1sh;

    const int t = threadIdx.x;
    const int bg = blockIdx.x, b = bg >> 2, g = bg & 3;
    const int c = blockIdx.y;           // 0..15
    const int lane = t & 63;
    const int r = t >> 7, d = t & 127;
    const float scale = 0.088388347648318447f;  // 1/sqrt(128)

    if (c == 15 && t == 0) {
        float s = 0.f;
        #pragma unroll
        for (int i = 0; i < 32; i++) s += ssqp1[i * 4 + b];
        rms1sh = rsqrtf(s * (1.f / 1024.f) + EPS_);
    }

    const float posf = (float)pos[b];
    const int j = d & 63;
    const float invf = exp2f(-(float)j * 0.31143075889569021f);  // 1e6^(-j/64)
    const float ang = posf * invf;
    const float cs = cosf(ang), sn = sinf(ang);
    const int pd = (d < 64) ? d + 64 : d - 64;

    // q: reduce 32 split-K chunks (UNSCALED -- head-norm is scale-invariant)
    float qraw = 0.f;
    {
        const int n = (2 * g + r) * 128 + d;
        #pragma unroll
        for (int cc = 0; cc < 32; cc++) qraw += qkvp[((size_t)cc * 4 + b) * 2048 + n];
    }
    ql[r][d] = qraw;
    float ssq = wave_reduce_sum(qraw * qraw);
    if (lane == 0) red[t >> 6] = ssq;
    __syncthreads();  // (A)
    const float rms_q = rsqrtf((red[r * 2] + red[r * 2 + 1]) * (1.f / 128.f) + EPS_);
    float qv = qraw * rms_q * qnw[d];
    float qp = ql[r][pd] * rms_q * qnw[pd];
    float qro = qv * cs + ((d < 64) ? -qp : qp) * sn;

    // new k/v: only chunk 15
    float kvraw = 0.f;
    if (c == 15) {
        const int base = (t < 128) ? (1024 + g * 128 + d) : (1536 + g * 128 + d);
        #pragma unroll
        for (int cc = 0; cc < 32; cc++) kvraw += qkvp[((size_t)cc * 4 + b) * 2048 + base];
    }
    float kss = wave_reduce_sum((t < 128) ? kvraw * kvraw : 0.f);
    __syncthreads();  // (B)
    ql[r][d] = qro;
    if (lane == 0 && t < 128) red[t >> 6] = kss;
    if (c == 15) { if (t < 128) Kl[32][d] = kvraw; else Vl[32][d] = kvraw; }
    __syncthreads();  // (C)
    float newkv = 0.f;
    if (c == 15) {
        if (t < 128) {
            const float rms_k = rsqrtf((red[0] + red[1]) * (1.f / 128.f) + EPS_);
            float kv_ = Kl[32][d] * rms_k * knw[d];
            float kp  = Kl[32][pd] * rms_k * knw[pd];
            newkv = kv_ * cs + ((d < 64) ? -kp : kp) * sn;
        } else {
            newkv = Vl[32][d] * rms1sh;      // deferred rms1 on V
        }
    }
    __syncthreads();  // (D)
    const size_t out_bg = (size_t)bg * (513 * 128);
    if (c == 15) {
        if (t < 128) { Kl[32][d] = newkv; kout[out_bg + 512 * 128 + d] = newkv; }
        else         { Vl[32][d] = newkv; vout[out_bg + 512 * 128 + d] = newkv; }
    }

    // KV tile (32 keys) load into LDS + copy to output cache (NT float4)
    const size_t in_bg = (size_t)bg * (512 * 128);
    const int s0 = c * 32;
    #pragma unroll
    for (int i = 0; i < 4; i++) {
        int f4 = i * 256 + t;
        int row = f4 >> 5, d0 = (f4 & 31) * 4;
        float4 k4 = ntld4(kin + in_bg + (size_t)(s0 + row) * 128 + d0);
        float4 v4 = ntld4(vin + in_bg + (size_t)(s0 + row) * 128 + d0);
        Kl[row][d0] = k4.x; Kl[row][d0 + 1] = k4.y; Kl[row][d0 + 2] = k4.z; Kl[row][d0 + 3] = k4.w;
        Vl[row][d0] = v4.x; Vl[row][d0 + 1] = v4.y; Vl[row][d0 + 2] = v4.z; Vl[row][d0 + 3] = v4.w;
        ntst4(kout + out_bg + (size_t)(s0 + row) * 128 + d0, k4);
        ntst4(vout + out_bg + (size_t)(s0 + row) * 128 + d0, v4);
    }
    __syncthreads();  // (E)

    // scores
    const int nk = (c == 15) ? 33 : 32;
    const int si = d;
    float sv = -1e30f;
    if (si < nk) {
        float a = 0.f;
        #pragma unroll 8
        for (int dd = 0; dd < 128; dd++) a += ql[r][dd] * Kl[si][dd];
        sv = a * scale;
    }
    float mv = wave_reduce_max(sv);
    if (lane == 0) red[t >> 6] = mv;
    __syncthreads();
    const float m = fmaxf(red[r * 2], red[r * 2 + 1]);
    float p = (si < nk) ? expf(sv - m) : 0.f;
    if (si < nk) sc[r][si] = p;
    float lsum = wave_reduce_sum(p);
    __syncthreads();
    if (lane == 0) red[t >> 6] = lsum;
    __syncthreads();
    const float lr = red[r * 2] + red[r * 2 + 1];
    if (d == 0) {
        mlpart[(size_t)((bg * 2 + r) * 16 + c) * 2 + 0] = m;
        mlpart[(size_t)((bg * 2 + r) * 16 + c) * 2 + 1] = lr;
    }
    float o = 0.f;
    for (int s2 = 0; s2 < nk; s2++) o += sc[r][s2] * Vl[s2][d];
    opart[(size_t)((bg * 2 + r) * 16 + c) * 128 + d] = o;
}

// ---------------- o-proj GEMV (flash-combine prologue): grid (4, 32) ----------------
__global__ __launch_bounds__(256) void k_oproj(
    const float* __restrict__ atto, const float* __restrict__ atml,
    const float* __restrict__ Wo_l, float* __restrict__ opp)
{
    __shared__ float xsl[128];
    __shared__ float4 accbuf[1024];
    const int t = threadIdx.x;
    const int ks = blockIdx.y, k0 = ks * 32, cb = blockIdx.x;
    gemv_core<8, 1024>(Wo_l, 1024, cb * 256, k0, xsl, accbuf, opp, cb, ks, [&]() {
        if (t < 128) {
            const int kk = t & 31, b = t >> 5;
            const int nrow = k0 + kk;
            const int head = nrow >> 7, dh = nrow & 127;
            const int g = head >> 1, rr = head & 1;
            const size_t base = (size_t)((b * 4 + g) * 2 + rr) * 16;
            float mc[16], lc[16], M = -1e30f;
            #pragma unroll
            for (int cc = 0; cc < 16; cc++) {
                mc[cc] = atml[(base + cc) * 2];
                lc[cc] = atml[(base + cc) * 2 + 1];
                M = fmaxf(M, mc[cc]);
            }
            float Ls = 0.f, o = 0.f;
            #pragma unroll
            for (int cc = 0; cc < 16; cc++) {
                float wch = expf(mc[cc] - M);
                Ls += lc[cc] * wch;
                o += atto[(base + cc) * 128 + dh] * wch;
            }
            xsl[kk * 4 + b] = o / Ls;
        }
        __syncthreads();
    });
}

// ---------------- gate/up: grid (8, 32) = 256 blocks; 3 column-units/block, single fold ----------------
__global__ __launch_bounds__(256) void k_gateup(
    const float* __restrict__ hA, const float* __restrict__ opp,
    const float* __restrict__ ln2,
    const float* __restrict__ Wg_l, const float* __restrict__ Wu_l,
    float* __restrict__ hB, float* __restrict__ ssqp2, float* __restrict__ gup)
{
    __shared__ float xsl[128];
    __shared__ float4 accbuf[1024];
    __shared__ float sred[128];
    const int t = threadIdx.x;
    const int ks = blockIdx.y, k0 = ks * 32, bx = blockIdx.x;
    const int wv = t >> 6, lane = t & 63;
    const int u0 = bx * 3;

    // preload unit 0 weights (NT)
    float4 wA[8], wB[8];
    {
        const float* Wp = ((u0 < 12) ? (Wg_l + u0 * 256) : (Wu_l + (u0 - 12) * 256))
                          + (size_t)(k0 + wv * 8) * 3072 + lane * 4;
        #pragma unroll
        for (int i = 0; i < 8; i++) wA[i] = ntld4(Wp + (size_t)i * 3072);
    }

    // fold + ln2 prologue (ONCE for all 3 units)
    if (t < 128) {
        const int row = t >> 2, b = t & 3;
        const int gr = k0 + row;
        float hn = hA[b * 1024 + gr];
        #pragma unroll 16
        for (int c = 0; c < 32; c++) hn += opp[(size_t)(c * 4 + b) * 1024 + gr];
        sred[t] = hn * hn;
        xsl[row * 4 + b] = hn * ln2[gr];
        if (bx == 0) hB[b * 1024 + gr] = hn;
    }
    __syncthreads();
    if (bx == 0 && t < 4) {
        float s = 0.f;
        #pragma unroll
        for (int r = 0; r < 32; r++) s += sred[r * 4 + t];
        ssqp2[ks * 4 + t] = s;
    }

    const float4* xs4 = (const float4*)xsl;
    #pragma unroll
    for (int j = 0; j < 3; j++) {
        const int u = u0 + j;
        if (j < 2) {   // prefetch next unit before the LDS reduce
            const int un = u0 + j + 1;
            const float* Wpn = ((un < 12) ? (Wg_l + un * 256) : (Wu_l + (un - 12) * 256))
                               + (size_t)(k0 + wv * 8) * 3072 + lane * 4;
            float4* wn = (j == 0) ? wB : wA;
            #pragma unroll
            for (int i = 0; i < 8; i++) wn[i] = ntld4(Wpn + (size_t)i * 3072);
        }
        const float4* wc = (j == 1) ? wB : wA;
        float4 a0 = {0,0,0,0}, a1 = {0,0,0,0}, a2 = {0,0,0,0}, a3 = {0,0,0,0};
        #pragma unroll
        for (int i = 0; i < 8; i++) {
            float4 w4 = wc[i];
            float4 xb = xs4[wv * 8 + i];
            a0.x += w4.x * xb.x; a0.y += w4.y * xb.x; a0.z += w4.z * xb.x; a0.w += w4.w * xb.x;
            a1.x += w4.x * xb.y; a1.y += w4.y * xb.y; a1.z += w4.z * xb.y; a1.w += w4.w * xb.y;
            a2.x += w4.x * xb.z; a2.y += w4.y * xb.z; a2.z += w4.z * xb.z; a2.w += w4.w * xb.z;
            a3.x += w4.x * xb.w; a3.y += w4.y * xb.w; a3.z += w4.z * xb.w; a3.w += w4.w * xb.w;
        }
        accbuf[(wv * 64 + lane) * 4 + 0] = a0;
        accbuf[(wv * 64 + lane) * 4 + 1] = a1;
        accbuf[(wv * 64 + lane) * 4 + 2] = a2;
        accbuf[(wv * 64 + lane) * 4 + 3] = a3;
        __syncthreads();
        const int l2 = t >> 2, b2 = t & 3;
        float4 s0 = accbuf[(0 * 64 + l2) * 4 + b2];
        float4 s1 = accbuf[(1 * 64 + l2) * 4 + b2];
        float4 s2 = accbuf[(2 * 64 + l2) * 4 + b2];
        float4 s3 = accbuf[(3 * 64 + l2) * 4 + b2];
        float4 s;
        s.x = s0.x + s1.x + s2.x + s3.x;
        s.y = s0.y + s1.y + s2.y + s3.y;
        s.z = s0.z + s1.z + s2.z + s3.z;
        s.w = s0.w + s1.w + s2.w + s3.w;
        const int ucol0 = (u < 12) ? u * 256 : 3072 + (u - 12) * 256;
        *(float4*)(gup + ((size_t)ks * 4 + b2) * 6144 + ucol0 + l2 * 4) = s;
        __syncthreads();
    }
}

// ---------------- down: deferred rms2 before SiLU. grid (4, 48) ----------------
__global__ __launch_bounds__(256) void k_down(
    const float* __restrict__ gup, const float* __restrict__ ssqp2,
    const float* __restrict__ Wd_l, float* __restrict__ dwp)
{
    __shared__ float xsl[256];
    __shared__ float4 accbuf[1024];
    __shared__ float rmsb[4];
    const int t = threadIdx.x;
    const int ks = blockIdx.y, k0 = ks * 64, cb = blockIdx.x;
    gemv_core<16, 1024>(Wd_l, 1024, cb * 256, k0, xsl, accbuf, dwp, cb, ks, [&]() {
        if (t < 4) {
            float s = 0.f;
            #pragma unroll
            for (int i = 0; i < 32; i++) s += ssqp2[i * 4 + t];
            rmsb[t] = rsqrtf(s * (1.f / 1024.f) + EPS_);
        }
        __syncthreads();
        const int b = t >> 6, kk = t & 63;
        const float rm = rmsb[b];
        float gg = 0.f, uu = 0.f;
        #pragma unroll 8
        for (int cc = 0; cc < 32; cc++) {
            gg += gup[((size_t)cc * 4 + b) * 6144 + k0 + kk];
            uu += gup[((size_t)cc * 4 + b) * 6144 + 3072 + k0 + kk];
        }
        gg *= rm; uu *= rm;
        xsl[kk * 4 + b] = gg / (1.f + expf(-gg)) * uu;
        __syncthreads();
    });
}

// ---------------- head: fold h_final rows; UNSCALED x = h*normw. grid (16, 32) ----------------
__global__ __launch_bounds__(256) void k_head(
    const float* __restrict__ hB, const float* __restrict__ dwp,
    const float* __restrict__ normw, const float* __restrict__ headw,
    float* __restrict__ xfu, float* __restrict__ ssqpF, float* __restrict__ hdp)
{
    __shared__ float xsl[128];
    __shared__ float4 accbuf[1024];
    __shared__ float sred[128];
    const int t = threadIdx.x;
    const int ks = blockIdx.y, k0 = ks * 32, cb = blockIdx.x;
    gemv_core<8, 4096>(headw, 4096, cb * 256, k0, xsl, accbuf, hdp, cb, ks, [&]() {
        if (t < 128) {
            const int row = t >> 2, b = t & 3;
            const int gr = k0 + row;
            float hn = hB[b * 1024 + gr];
            #pragma unroll 16
            for (int c = 0; c < 48; c++) hn += dwp[(size_t)(c * 4 + b) * 1024 + gr];
            sred[t] = hn * hn;
            const float x = hn * normw[gr];
            xsl[row * 4 + b] = x;
            if (cb == 0) xfu[b * 1024 + gr] = x;
        }
        __syncthreads();
        if (cb == 0 && t < 4) {
            float s = 0.f;
            #pragma unroll
            for (int r = 0; r < 32; r++) s += sred[r * 4 + t];
            ssqpF[ks * 4 + t] = s;
        }
    });
}

// ---------------- logits reduce + deferred rms_f + past: grid 16 ----------------
__global__ __launch_bounds__(256) void k_logits(
    const float* __restrict__ hdp, const float* __restrict__ ssqpF,
    const float* __restrict__ xfu,
    float* __restrict__ logits, float* __restrict__ past)
{
    __shared__ float rsh;
    const int t = threadIdx.x, bid = blockIdx.x;
    const int b = bid >> 2;
    if (t == 0) {
        float s = 0.f;
        #pragma unroll
        for (int i = 0; i < 32; i++) s += ssqpF[i * 4 + b];
        rsh = rsqrtf(s * (1.f / 1024.f) + EPS_);
    }
    __syncthreads();
    const float rf = rsh;
    const int t4 = bid * 256 + t;       // 0..4095 float4s; b = t4>>10
    const int n4 = t4 & 1023;
    float4 s = {0.f, 0.f, 0.f, 0.f};
    #pragma unroll
    for (int c = 0; c < 32; c++) {
        float4 v = *(const float4*)(hdp + ((size_t)c * 4 + b) * 4096 + n4 * 4);
        s.x += v.x; s.y += v.y; s.z += v.z; s.w += v.w;
    }
    s.x *= rf; s.y *= rf; s.z *= rf; s.w *= rf;
    *(float4*)(logits + (size_t)t4 * 4) = s;
    if (t < 64) {
        const int p = bid * 64 + t;
        const int i4 = p & 255;
        float4 x = *(const float4*)(xfu + b * 1024 + i4 * 4);
        x.x *= rf; x.y *= rf; x.z *= rf; x.w *= rf;
        *(float4*)(past + (size_t)p * 4) = x;
    }
}

extern "C" void kernel_launch(void* const* d_in, const int* in_sizes, int n_in,
                              void* d_out, int out_size, void* d_ws, size_t ws_size,
                              hipStream_t stream)
{
    const int*   cb0   = (const int*)d_in[0];
    const int*   cb1   = (const int*)d_in[1];
    const float* trail = (const float*)d_in[2];
    const float* kvin  = (const float*)d_in[3];
    const int*   pos   = (const int*)d_in[4];
    const float* cb0e  = (const float*)d_in[5];
    const float* cpe   = (const float*)d_in[6];
    const float* Wq    = (const float*)d_in[7];
    const float* Wk    = (const float*)d_in[8];
    const float* Wv    = (const float*)d_in[9];
    const float* Wo    = (const float*)d_in[10];
    const float* qnw   = (const float*)d_in[11];
    const float* knw   = (const float*)d_in[12];
    const float* ln1   = (const float*)d_in[13];
    const float* ln2   = (const float*)d_in[14];
    const float* Wg    = (const float*)d_in[15];
    const float* Wu    = (const float*)d_in[16];
    const float* Wd    = (const float*)d_in[17];
    const float* normw = (const float*)d_in[18];
    const float* headw = (const float*)d_in[19];

    float* out    = (float*)d_out;
    float* logits = out;
    float* kvout  = out + 16384;
    float* past   = out + 16384 + (size_t)2 * L_ * B_ * KVH_ * (S_ + 1) * HD_;
    float* ws = (float*)d_ws;

    float* hA    = ws + WS_HA;
    float* hB    = ws + WS_HB;
    float* xfu   = ws + WS_XFU;
    float* ssqp1 = ws + WS_SSQ1;
    float* ssqp2 = ws + WS_SSQ2;
    float* ssqpF = ws + WS_SSQF;
    float* qkvp  = ws + WS_QKVP;
    float* atto  = ws + WS_ATTO;
    float* atml  = ws + WS_ATML;
    float* opp   = ws + WS_OPP;
    float* gup   = ws + WS_GUP;
    float* dwp   = ws + WS_DWP;
    float* hdp   = ws + WS_HDP;

    const size_t IN_PLANE  = (size_t)B_ * KVH_ * S_ * HD_;
    const size_t OUT_PLANE = (size_t)B_ * KVH_ * (S_ + 1) * HD_;

    for (int l = 0; l < L_; l++) {
        if (l == 0)
            k_qkv<true><<<dim3(8, 32), 256, 0, stream>>>(
                hB, dwp, cb0, cb1, trail, cb0e, cpe, ln1 + (size_t)l * H_,
                Wq + (size_t)l * H_ * 1024, Wk + (size_t)l * H_ * 512,
                Wv + (size_t)l * H_ * 512, hA, ssqp1, qkvp);
        else
            k_qkv<false><<<dim3(8, 32), 256, 0, stream>>>(
                hB, dwp, cb0, cb1, trail, cb0e, cpe, ln1 + (size_t)l * H_,
                Wq + (size_t)l * H_ * 1024, Wk + (size_t)l * H_ * 512,
                Wv + (size_t)l * H_ * 512, hA, ssqp1, qkvp);
        k_attn<<<dim3(16, 16), 256, 0, stream>>>(
            qkvp, ssqp1, qnw + (size_t)l * HD_, knw + (size_t)l * HD_,
            kvin + (size_t)(2 * l) * IN_PLANE, kvin + (size_t)(2 * l + 1) * IN_PLANE,
            kvout + (size_t)(2 * l) * OUT_PLANE, kvout + (size_t)(2 * l + 1) * OUT_PLANE,
            pos, atto, atml);
        k_oproj<<<dim3(4, 32), 256, 0, stream>>>(
            atto, atml, Wo + (size_t)l * 1024 * H_, opp);
        k_gateup<<<dim3(8, 32), 256, 0, stream>>>(
            hA, opp, ln2 + (size_t)l * H_,
            Wg + (size_t)l * H_ * I_, Wu + (size_t)l * H_ * I_, hB, ssqp2, gup);
        k_down<<<dim3(4, 48), 256, 0, stream>>>(
            gup, ssqp2, Wd + (size_t)l * I_ * H_, dwp);
    }
    k_head<<<dim3(16, 32), 256, 0, stream>>>(hB, dwp, normw, headw, xfu, ssqpF, hdp);
    k_logits<<<16, 256, 0, stream>>>(hdp, ssqpF, xfu, logits, past);
}

// Round 17
// 1081.635 us; speedup vs baseline: 1.1967x; 1.0092x over previous
//
#include <hip/hip_runtime.h>
#include <math.h>

#define L_  28
#define H_  1024
#define NH_ 8
#define KVH_ 4
#define HD_ 128
#define I_  3072
#define VC_ 4096
#define B_  4
#define S_  512
#define EPS_ 1e-6f

// ---- workspace layout (float offsets) ----
#define WS_HA    0            // [4][1024] h after attn-input fold (h3)
#define WS_HB    4096         // [4][1024] h after mlp-input fold (h4)
#define WS_XFU   8192         // [4][1024] unscaled final-normed x
#define WS_SSQ1  12288        // [32 ks][4 b] ssq partials of h3
#define WS_SSQ2  12416        // [32 ks][4 b] ssq partials of h4
#define WS_SSQF  12544        // [32 ks][4 b] ssq partials of h_final
#define WS_QKVP  12672        // [32][4][2048]
#define WS_ATTO  274816       // [16 bg][2 r][16 c][128]
#define WS_ATML  340352       // [16 bg][2 r][16 c][2]
#define WS_OPP   341376       // [32][4][1024]
#define WS_GUP   472448       // [32][4][6144]
#define WS_DWP   1258880      // [48][4][1024]
#define WS_HDP   1455488      // [32][4][4096]

typedef float v4f __attribute__((ext_vector_type(4)));

__device__ __forceinline__ float4 ntld4(const float* p) {
    v4f r = __builtin_nontemporal_load(reinterpret_cast<const v4f*>(p));
    return make_float4(r.x, r.y, r.z, r.w);
}
__device__ __forceinline__ void ntst4(float* p, float4 v) {
    v4f r = {v.x, v.y, v.z, v.w};
    __builtin_nontemporal_store(r, reinterpret_cast<v4f*>(p));
}

__device__ __forceinline__ float wave_reduce_sum(float v) {
    #pragma unroll
    for (int off = 32; off; off >>= 1) v += __shfl_down(v, off);
    return v;
}
__device__ __forceinline__ float wave_reduce_max(float v) {
    #pragma unroll
    for (int off = 32; off; off >>= 1) v = fmaxf(v, __shfl_down(v, off));
    return v;
}

// ---------------- GEMV core: NT weight preload -> prologue -> FMA -> LDS reduce -> store ----------------
template<int RPW, int NTOT, typename F>
__device__ __forceinline__ void gemv_core(
    const float* __restrict__ W, int ldw, int wcol0, int k0,
    float* __restrict__ xsl, float4* __restrict__ accbuf,
    float* __restrict__ pp, int colblk, int ks, F&& prologue)
{
    const int t = threadIdx.x;
    const int wv = t >> 6, lane = t & 63;
    const float* Wp = W + (size_t)(k0 + wv * RPW) * ldw + wcol0 + lane * 4;
    float4 wreg[RPW];
    #pragma unroll
    for (int i = 0; i < RPW; i++) wreg[i] = ntld4(Wp + (size_t)i * ldw);
    prologue();   // fills xsl; ends with __syncthreads()
    const float4* xs4 = (const float4*)xsl;
    float4 a0 = {0,0,0,0}, a1 = {0,0,0,0}, a2 = {0,0,0,0}, a3 = {0,0,0,0};
    #pragma unroll
    for (int i = 0; i < RPW; i++) {
        float4 w4 = wreg[i];
        float4 xb = xs4[wv * RPW + i];
        a0.x += w4.x * xb.x; a0.y += w4.y * xb.x; a0.z += w4.z * xb.x; a0.w += w4.w * xb.x;
        a1.x += w4.x * xb.y; a1.y += w4.y * xb.y; a1.z += w4.z * xb.y; a1.w += w4.w * xb.y;
        a2.x += w4.x * xb.z; a2.y += w4.y * xb.z; a2.z += w4.z * xb.z; a2.w += w4.w * xb.z;
        a3.x += w4.x * xb.w; a3.y += w4.y * xb.w; a3.z += w4.z * xb.w; a3.w += w4.w * xb.w;
    }
    accbuf[(wv * 64 + lane) * 4 + 0] = a0;
    accbuf[(wv * 64 + lane) * 4 + 1] = a1;
    accbuf[(wv * 64 + lane) * 4 + 2] = a2;
    accbuf[(wv * 64 + lane) * 4 + 3] = a3;
    __syncthreads();
    const int l2 = t >> 2, b2 = t & 3;
    float4 s0 = accbuf[(0 * 64 + l2) * 4 + b2];
    float4 s1 = accbuf[(1 * 64 + l2) * 4 + b2];
    float4 s2 = accbuf[(2 * 64 + l2) * 4 + b2];
    float4 s3 = accbuf[(3 * 64 + l2) * 4 + b2];
    float4 s;
    s.x = s0.x + s1.x + s2.x + s3.x;
    s.y = s0.y + s1.y + s2.y + s3.y;
    s.z = s0.z + s1.z + s2.z + s3.z;
    s.w = s0.w + s1.w + s2.w + s3.w;
    *(float4*)(pp + ((size_t)ks * 4 + b2) * NTOT + colblk * 256 + l2 * 4) = s;
}

// ---------------- qkv (fused embed for l==0; fold+norm prologue): grid (8, 32) ----------------
template<bool FIRST>
__global__ __launch_bounds__(256) void k_qkv(
    const float* __restrict__ hPrev, const float* __restrict__ dwp,
    const int* __restrict__ cb0, const int* __restrict__ cb1,
    const float* __restrict__ trail, const float* __restrict__ cb0e,
    const float* __restrict__ cpe,
    const float* __restrict__ ln1,
    const float* __restrict__ Wq, const float* __restrict__ Wk,
    const float* __restrict__ Wv,
    float* __restrict__ hA, float* __restrict__ ssqp1, float* __restrict__ qkvp)
{
    __shared__ float xsl[128];
    __shared__ float4 accbuf[1024];
    __shared__ float sred[128];
    const int t = threadIdx.x;
    const int ks = blockIdx.y, k0 = ks * 32, cb = blockIdx.x;
    const float* W; int ldw, wcol0;
    if (cb < 4)      { W = Wq; ldw = 1024; wcol0 = cb * 256; }
    else if (cb < 6) { W = Wk; ldw = 512;  wcol0 = (cb - 4) * 256; }
    else             { W = Wv; ldw = 512;  wcol0 = (cb - 6) * 256; }
    gemv_core<8, 2048>(W, ldw, wcol0, k0, xsl, accbuf, qkvp, cb, ks, [&]() {
        if (t < 128) {
            const int row = t >> 2, b = t & 3;
            const int gr = k0 + row;
            float hn;
            if (FIRST) {
                hn = cb0e[(size_t)cb0[b] * 1024 + gr] + trail[b * 1024 + gr];
                #pragma unroll
                for (int j = 0; j < 15; j++)
                    hn += cpe[((size_t)j * 4096 + cb1[b * 15 + j]) * 1024 + gr];
            } else {
                hn = hPrev[b * 1024 + gr];
                #pragma unroll 16
                for (int c = 0; c < 48; c++) hn += dwp[(size_t)(c * 4 + b) * 1024 + gr];
            }
            sred[t] = hn * hn;
            xsl[row * 4 + b] = hn * ln1[gr];
            if (cb == 0) hA[b * 1024 + gr] = hn;
        }
        __syncthreads();
        if (cb == 0 && t < 4) {
            float s = 0.f;
            #pragma unroll
            for (int r = 0; r < 32; r++) s += sred[r * 4 + t];
            ssqp1[ks * 4 + t] = s;
        }
    });
}

// ---------------- attention flash chunk (KV loads HOISTED to registers): grid (16 bg, 16 c) ----------------
__global__ __launch_bounds__(256) void k_attn(
    const float* __restrict__ qkvp, const float* __restrict__ ssqp1,
    const float* __restrict__ qnw, const float* __restrict__ knw,
    const float* __restrict__ kin, const float* __restrict__ vin,
    float* __restrict__ kout, float* __restrict__ vout,
    const int* __restrict__ pos,
    float* __restrict__ opart, float* __restrict__ mlpart)
{
    __shared__ float Kl[33][129];
    __shared__ float Vl[33][129];
    __shared__ float ql[2][128];
    __shared__ float sc[2][36];
    __shared__ float red[8];
    __shared__ float rms1sh;

    const int t = threadIdx.x;
    const int bg = blockIdx.x, b = bg >> 2, g = bg & 3;
    const int c = blockIdx.y;           // 0..15
    const int lane = t & 63;
    const int r = t >> 7, d = t & 127;
    const float scale = 0.088388347648318447f;  // 1/sqrt(128)

    // ---- HOISTED: issue the bulk KV-tile loads FIRST so HBM fetch overlaps the q-phase ----
    const size_t in_bg = (size_t)bg * (512 * 128);
    const int s0 = c * 32;
    float4 kreg[4], vreg[4];
    #pragma unroll
    for (int i = 0; i < 4; i++) {
        const int f4 = i * 256 + t;
        const int row = f4 >> 5, d0 = (f4 & 31) * 4;
        kreg[i] = ntld4(kin + in_bg + (size_t)(s0 + row) * 128 + d0);
        vreg[i] = ntld4(vin + in_bg + (size_t)(s0 + row) * 128 + d0);
    }

    if (c == 15 && t == 0) {
        float s = 0.f;
        #pragma unroll
        for (int i = 0; i < 32; i++) s += ssqp1[i * 4 + b];
        rms1sh = rsqrtf(s * (1.f / 1024.f) + EPS_);
    }

    const float posf = (float)pos[b];
    const int j = d & 63;
    const float invf = exp2f(-(float)j * 0.31143075889569021f);  // 1e6^(-j/64)
    const float ang = posf * invf;
    const float cs = cosf(ang), sn = sinf(ang);
    const int pd = (d < 64) ? d + 64 : d - 64;

    // q: reduce 32 split-K chunks (UNSCALED -- head-norm is scale-invariant)
    float qraw = 0.f;
    {
        const int n = (2 * g + r) * 128 + d;
        #pragma unroll
        for (int cc = 0; cc < 32; cc++) qraw += qkvp[((size_t)cc * 4 + b) * 2048 + n];
    }
    ql[r][d] = qraw;
    float ssq = wave_reduce_sum(qraw * qraw);
    if (lane == 0) red[t >> 6] = ssq;
    __syncthreads();  // (A)
    const float rms_q = rsqrtf((red[r * 2] + red[r * 2 + 1]) * (1.f / 128.f) + EPS_);
    float qv = qraw * rms_q * qnw[d];
    float qp = ql[r][pd] * rms_q * qnw[pd];
    float qro = qv * cs + ((d < 64) ? -qp : qp) * sn;

    // new k/v: only chunk 15
    float kvraw = 0.f;
    if (c == 15) {
        const int base = (t < 128) ? (1024 + g * 128 + d) : (1536 + g * 128 + d);
        #pragma unroll
        for (int cc = 0; cc < 32; cc++) kvraw += qkvp[((size_t)cc * 4 + b) * 2048 + base];
    }
    float kss = wave_reduce_sum((t < 128) ? kvraw * kvraw : 0.f);
    __syncthreads();  // (B)
    ql[r][d] = qro;
    if (lane == 0 && t < 128) red[t >> 6] = kss;
    if (c == 15) { if (t < 128) Kl[32][d] = kvraw; else Vl[32][d] = kvraw; }
    __syncthreads();  // (C)
    float newkv = 0.f;
    if (c == 15) {
        if (t < 128) {
            const float rms_k = rsqrtf((red[0] + red[1]) * (1.f / 128.f) + EPS_);
            float kv_ = Kl[32][d] * rms_k * knw[d];
            float kp  = Kl[32][pd] * rms_k * knw[pd];
            newkv = kv_ * cs + ((d < 64) ? -kp : kp) * sn;
        } else {
            newkv = Vl[32][d] * rms1sh;      // deferred rms1 on V
        }
    }
    __syncthreads();  // (D)
    const size_t out_bg = (size_t)bg * (513 * 128);
    if (c == 15) {
        if (t < 128) { Kl[32][d] = newkv; kout[out_bg + 512 * 128 + d] = newkv; }
        else         { Vl[32][d] = newkv; vout[out_bg + 512 * 128 + d] = newkv; }
    }

    // KV tile: registers -> LDS + copy to output cache (NT float4)
    #pragma unroll
    for (int i = 0; i < 4; i++) {
        const int f4 = i * 256 + t;
        const int row = f4 >> 5, d0 = (f4 & 31) * 4;
        Kl[row][d0] = kreg[i].x; Kl[row][d0 + 1] = kreg[i].y;
        Kl[row][d0 + 2] = kreg[i].z; Kl[row][d0 + 3] = kreg[i].w;
        Vl[row][d0] = vreg[i].x; Vl[row][d0 + 1] = vreg[i].y;
        Vl[row][d0 + 2] = vreg[i].z; Vl[row][d0 + 3] = vreg[i].w;
        ntst4(kout + out_bg + (size_t)(s0 + row) * 128 + d0, kreg[i]);
        ntst4(vout + out_bg + (size_t)(s0 + row) * 128 + d0, vreg[i]);
    }
    __syncthreads();  // (E)

    // scores
    const int nk = (c == 15) ? 33 : 32;
    const int si = d;
    float sv = -1e30f;
    if (si < nk) {
        float a = 0.f;
        #pragma unroll 8
        for (int dd = 0; dd < 128; dd++) a += ql[r][dd] * Kl[si][dd];
        sv = a * scale;
    }
    float mv = wave_reduce_max(sv);
    if (lane == 0) red[t >> 6] = mv;
    __syncthreads();
    const float m = fmaxf(red[r * 2], red[r * 2 + 1]);
    float p = (si < nk) ? expf(sv - m) : 0.f;
    if (si < nk) sc[r][si] = p;
    float lsum = wave_reduce_sum(p);
    __syncthreads();
    if (lane == 0) red[t >> 6] = lsum;
    __syncthreads();
    const float lr = red[r * 2] + red[r * 2 + 1];
    if (d == 0) {
        mlpart[(size_t)((bg * 2 + r) * 16 + c) * 2 + 0] = m;
        mlpart[(size_t)((bg * 2 + r) * 16 + c) * 2 + 1] = lr;
    }
    float o = 0.f;
    for (int s2 = 0; s2 < nk; s2++) o += sc[r][s2] * Vl[s2][d];
    opart[(size_t)((bg * 2 + r) * 16 + c) * 128 + d] = o;
}

// ---------------- o-proj GEMV (flash-combine prologue): grid (4, 32) ----------------
__global__ __launch_bounds__(256) void k_oproj(
    const float* __restrict__ atto, const float* __restrict__ atml,
    const float* __restrict__ Wo_l, float* __restrict__ opp)
{
    __shared__ float xsl[128];
    __shared__ float4 accbuf[1024];
    const int t = threadIdx.x;
    const int ks = blockIdx.y, k0 = ks * 32, cb = blockIdx.x;
    gemv_core<8, 1024>(Wo_l, 1024, cb * 256, k0, xsl, accbuf, opp, cb, ks, [&]() {
        if (t < 128) {
            const int kk = t & 31, b = t >> 5;
            const int nrow = k0 + kk;
            const int head = nrow >> 7, dh = nrow & 127;
            const int g = head >> 1, rr = head & 1;
            const size_t base = (size_t)((b * 4 + g) * 2 + rr) * 16;
            float mc[16], lc[16], M = -1e30f;
            #pragma unroll
            for (int cc = 0; cc < 16; cc++) {
                mc[cc] = atml[(base + cc) * 2];
                lc[cc] = atml[(base + cc) * 2 + 1];
                M = fmaxf(M, mc[cc]);
            }
            float Ls = 0.f, o = 0.f;
            #pragma unroll
            for (int cc = 0; cc < 16; cc++) {
                float wch = expf(mc[cc] - M);
                Ls += lc[cc] * wch;
                o += atto[(base + cc) * 128 + dh] * wch;
            }
            xsl[kk * 4 + b] = o / Ls;
        }
        __syncthreads();
    });
}

// ---------------- gate/up: grid (8, 32) = 256 blocks; 3 column-units/block, single fold ----------------
__global__ __launch_bounds__(256) void k_gateup(
    const float* __restrict__ hA, const float* __restrict__ opp,
    const float* __restrict__ ln2,
    const float* __restrict__ Wg_l, const float* __restrict__ Wu_l,
    float* __restrict__ hB, float* __restrict__ ssqp2, float* __restrict__ gup)
{
    __shared__ float xsl[128];
    __shared__ float4 accbuf[1024];
    __shared__ float sred[128];
    const int t = threadIdx.x;
    const int ks = blockIdx.y, k0 = ks * 32, bx = blockIdx.x;
    const int wv = t >> 6, lane = t & 63;
    const int u0 = bx * 3;

    // preload unit 0 weights (NT)
    float4 wA[8], wB[8];
    {
        const float* Wp = ((u0 < 12) ? (Wg_l + u0 * 256) : (Wu_l + (u0 - 12) * 256))
                          + (size_t)(k0 + wv * 8) * 3072 + lane * 4;
        #pragma unroll
        for (int i = 0; i < 8; i++) wA[i] = ntld4(Wp + (size_t)i * 3072);
    }

    // fold + ln2 prologue (ONCE for all 3 units)
    if (t < 128) {
        const int row = t >> 2, b = t & 3;
        const int gr = k0 + row;
        float hn = hA[b * 1024 + gr];
        #pragma unroll 16
        for (int c = 0; c < 32; c++) hn += opp[(size_t)(c * 4 + b) * 1024 + gr];
        sred[t] = hn * hn;
        xsl[row * 4 + b] = hn * ln2[gr];
        if (bx == 0) hB[b * 1024 + gr] = hn;
    }
    __syncthreads();
    if (bx == 0 && t < 4) {
        float s = 0.f;
        #pragma unroll
        for (int r = 0; r < 32; r++) s += sred[r * 4 + t];
        ssqp2[ks * 4 + t] = s;
    }

    const float4* xs4 = (const float4*)xsl;
    #pragma unroll
    for (int j = 0; j < 3; j++) {
        const int u = u0 + j;
        if (j < 2) {   // prefetch next unit before the LDS reduce
            const int un = u0 + j + 1;
            const float* Wpn = ((un < 12) ? (Wg_l + un * 256) : (Wu_l + (un - 12) * 256))
                               + (size_t)(k0 + wv * 8) * 3072 + lane * 4;
            float4* wn = (j == 0) ? wB : wA;
            #pragma unroll
            for (int i = 0; i < 8; i++) wn[i] = ntld4(Wpn + (size_t)i * 3072);
        }
        const float4* wc = (j == 1) ? wB : wA;
        float4 a0 = {0,0,0,0}, a1 = {0,0,0,0}, a2 = {0,0,0,0}, a3 = {0,0,0,0};
        #pragma unroll
        for (int i = 0; i < 8; i++) {
            float4 w4 = wc[i];
            float4 xb = xs4[wv * 8 + i];
            a0.x += w4.x * xb.x; a0.y += w4.y * xb.x; a0.z += w4.z * xb.x; a0.w += w4.w * xb.x;
            a1.x += w4.x * xb.y; a1.y += w4.y * xb.y; a1.z += w4.z * xb.y; a1.w += w4.w * xb.y;
            a2.x += w4.x * xb.z; a2.y += w4.y * xb.z; a2.z += w4.z * xb.z; a2.w += w4.w * xb.z;
            a3.x += w4.x * xb.w; a3.y += w4.y * xb.w; a3.z += w4.z * xb.w; a3.w += w4.w * xb.w;
        }
        accbuf[(wv * 64 + lane) * 4 + 0] = a0;
        accbuf[(wv * 64 + lane) * 4 + 1] = a1;
        accbuf[(wv * 64 + lane) * 4 + 2] = a2;
        accbuf[(wv * 64 + lane) * 4 + 3] = a3;
        __syncthreads();
        const int l2 = t >> 2, b2 = t & 3;
        float4 s0 = accbuf[(0 * 64 + l2) * 4 + b2];
        float4 s1 = accbuf[(1 * 64 + l2) * 4 + b2];
        float4 s2 = accbuf[(2 * 64 + l2) * 4 + b2];
        float4 s3 = accbuf[(3 * 64 + l2) * 4 + b2];
        float4 s;
        s.x = s0.x + s1.x + s2.x + s3.x;
        s.y = s0.y + s1.y + s2.y + s3.y;
        s.z = s0.z + s1.z + s2.z + s3.z;
        s.w = s0.w + s1.w + s2.w + s3.w;
        const int ucol0 = (u < 12) ? u * 256 : 3072 + (u - 12) * 256;
        *(float4*)(gup + ((size_t)ks * 4 + b2) * 6144 + ucol0 + l2 * 4) = s;
        __syncthreads();
    }
}

// ---------------- down: deferred rms2 before SiLU. grid (4, 48) ----------------
__global__ __launch_bounds__(256) void k_down(
    const float* __restrict__ gup, const float* __restrict__ ssqp2,
    const float* __restrict__ Wd_l, float* __restrict__ dwp)
{
    __shared__ float xsl[256];
    __shared__ float4 accbuf[1024];
    __shared__ float rmsb[4];
    const int t = threadIdx.x;
    const int ks = blockIdx.y, k0 = ks * 64, cb = blockIdx.x;
    gemv_core<16, 1024>(Wd_l, 1024, cb * 256, k0, xsl, accbuf, dwp, cb, ks, [&]() {
        if (t < 4) {
            float s = 0.f;
            #pragma unroll
            for (int i = 0; i < 32; i++) s += ssqp2[i * 4 + t];
            rmsb[t] = rsqrtf(s * (1.f / 1024.f) + EPS_);
        }
        __syncthreads();
        const int b = t >> 6, kk = t & 63;
        const float rm = rmsb[b];
        float gg = 0.f, uu = 0.f;
        #pragma unroll 8
        for (int cc = 0; cc < 32; cc++) {
            gg += gup[((size_t)cc * 4 + b) * 6144 + k0 + kk];
            uu += gup[((size_t)cc * 4 + b) * 6144 + 3072 + k0 + kk];
        }
        gg *= rm; uu *= rm;
        xsl[kk * 4 + b] = gg / (1.f + expf(-gg)) * uu;
        __syncthreads();
    });
}

// ---------------- head: fold h_final rows; UNSCALED x = h*normw. grid (16, 32) ----------------
__global__ __launch_bounds__(256) void k_head(
    const float* __restrict__ hB, const float* __restrict__ dwp,
    const float* __restrict__ normw, const float* __restrict__ headw,
    float* __restrict__ xfu, float* __restrict__ ssqpF, float* __restrict__ hdp)
{
    __shared__ float xsl[128];
    __shared__ float4 accbuf[1024];
    __shared__ float sred[128];
    const int t = threadIdx.x;
    const int ks = blockIdx.y, k0 = ks * 32, cb = blockIdx.x;
    gemv_core<8, 4096>(headw, 4096, cb * 256, k0, xsl, accbuf, hdp, cb, ks, [&]() {
        if (t < 128) {
            const int row = t >> 2, b = t & 3;
            const int gr = k0 + row;
            float hn = hB[b * 1024 + gr];
            #pragma unroll 16
            for (int c = 0; c < 48; c++) hn += dwp[(size_t)(c * 4 + b) * 1024 + gr];
            sred[t] = hn * hn;
            const float x = hn * normw[gr];
            xsl[row * 4 + b] = x;
            if (cb == 0) xfu[b * 1024 + gr] = x;
        }
        __syncthreads();
        if (cb == 0 && t < 4) {
            float s = 0.f;
            #pragma unroll
            for (int r = 0; r < 32; r++) s += sred[r * 4 + t];
            ssqpF[ks * 4 + t] = s;
        }
    });
}

// ---------------- logits reduce + deferred rms_f + past: grid 16 ----------------
__global__ __launch_bounds__(256) void k_logits(
    const float* __restrict__ hdp, const float* __restrict__ ssqpF,
    const float* __restrict__ xfu,
    float* __restrict__ logits, float* __restrict__ past)
{
    __shared__ float rsh;
    const int t = threadIdx.x, bid = blockIdx.x;
    const int b = bid >> 2;
    if (t == 0) {
        float s = 0.f;
        #pragma unroll
        for (int i = 0; i < 32; i++) s += ssqpF[i * 4 + b];
        rsh = rsqrtf(s * (1.f / 1024.f) + EPS_);
    }
    __syncthreads();
    const float rf = rsh;
    const int t4 = bid * 256 + t;       // 0..4095 float4s; b = t4>>10
    const int n4 = t4 & 1023;
    float4 s = {0.f, 0.f, 0.f, 0.f};
    #pragma unroll
    for (int c = 0; c < 32; c++) {
        float4 v = *(const float4*)(hdp + ((size_t)c * 4 + b) * 4096 + n4 * 4);
        s.x += v.x; s.y += v.y; s.z += v.z; s.w += v.w;
    }
    s.x *= rf; s.y *= rf; s.z *= rf; s.w *= rf;
    *(float4*)(logits + (size_t)t4 * 4) = s;
    if (t < 64) {
        const int p = bid * 64 + t;
        const int i4 = p & 255;
        float4 x = *(const float4*)(xfu + b * 1024 + i4 * 4);
        x.x *= rf; x.y *= rf; x.z *= rf; x.w *= rf;
        *(float4*)(past + (size_t)p * 4) = x;
    }
}

extern "C" void kernel_launch(void* const* d_in, const int* in_sizes, int n_in,
                              void* d_out, int out_size, void* d_ws, size_t ws_size,
                              hipStream_t stream)
{
    const int*   cb0   = (const int*)d_in[0];
    const int*   cb1   = (const int*)d_in[1];
    const float* trail = (const float*)d_in[2];
    const float* kvin  = (const float*)d_in[3];
    const int*   pos   = (const int*)d_in[4];
    const float* cb0e  = (const float*)d_in[5];
    const float* cpe   = (const float*)d_in[6];
    const float* Wq    = (const float*)d_in[7];
    const float* Wk    = (const float*)d_in[8];
    const float* Wv    = (const float*)d_in[9];
    const float* Wo    = (const float*)d_in[10];
    const float* qnw   = (const float*)d_in[11];
    const float* knw   = (const float*)d_in[12];
    const float* ln1   = (const float*)d_in[13];
    const float* ln2   = (const float*)d_in[14];
    const float* Wg    = (const float*)d_in[15];
    const float* Wu    = (const float*)d_in[16];
    const float* Wd    = (const float*)d_in[17];
    const float* normw = (const float*)d_in[18];
    const float* headw = (const float*)d_in[19];

    float* out    = (float*)d_out;
    float* logits = out;
    float* kvout  = out + 16384;
    float* past   = out + 16384 + (size_t)2 * L_ * B_ * KVH_ * (S_ + 1) * HD_;
    float* ws = (float*)d_ws;

    float* hA    = ws + WS_HA;
    float* hB    = ws + WS_HB;
    float* xfu   = ws + WS_XFU;
    float* ssqp1 = ws + WS_SSQ1;
    float* ssqp2 = ws + WS_SSQ2;
    float* ssqpF = ws + WS_SSQF;
    float* qkvp  = ws + WS_QKVP;
    float* atto  = ws + WS_ATTO;
    float* atml  = ws + WS_ATML;
    float* opp   = ws + WS_OPP;
    float* gup   = ws + WS_GUP;
    float* dwp   = ws + WS_DWP;
    float* hdp   = ws + WS_HDP;

    const size_t IN_PLANE  = (size_t)B_ * KVH_ * S_ * HD_;
    const size_t OUT_PLANE = (size_t)B_ * KVH_ * (S_ + 1) * HD_;

    for (int l = 0; l < L_; l++) {
        if (l == 0)
            k_qkv<true><<<dim3(8, 32), 256, 0, stream>>>(
                hB, dwp, cb0, cb1, trail, cb0e, cpe, ln1 + (size_t)l * H_,
                Wq + (size_t)l * H_ * 1024, Wk + (size_t)l * H_ * 512,
                Wv + (size_t)l * H_ * 512, hA, ssqp1, qkvp);
        else
            k_qkv<false><<<dim3(8, 32), 256, 0, stream>>>(
                hB, dwp, cb0, cb1, trail, cb0e, cpe, ln1 + (size_t)l * H_,
                Wq + (size_t)l * H_ * 1024, Wk + (size_t)l * H_ * 512,
                Wv + (size_t)l * H_ * 512, hA, ssqp1, qkvp);
        k_attn<<<dim3(16, 16), 256, 0, stream>>>(
            qkvp, ssqp1, qnw + (size_t)l * HD_, knw + (size_t)l * HD_,
            kvin + (size_t)(2 * l) * IN_PLANE, kvin + (size_t)(2 * l + 1) * IN_PLANE,
            kvout + (size_t)(2 * l) * OUT_PLANE, kvout + (size_t)(2 * l + 1) * OUT_PLANE,
            pos, atto, atml);
        k_oproj<<<dim3(4, 32), 256, 0, stream>>>(
            atto, atml, Wo + (size_t)l * 1024 * H_, opp);
        k_gateup<<<dim3(8, 32), 256, 0, stream>>>(
            hA, opp, ln2 + (size_t)l * H_,
            Wg + (size_t)l * H_ * I_, Wu + (size_t)l * H_ * I_, hB, ssqp2, gup);
        k_down<<<dim3(4, 48), 256, 0, stream>>>(
            gup, ssqp2, Wd + (size_t)l * I_ * H_, dwp);
    }
    k_head<<<dim3(16, 32), 256, 0, stream>>>(hB, dwp, normw, headw, xfu, ssqpF, hdp);
    k_logits<<<16, 256, 0, stream>>>(hdp, ssqpF, xfu, logits, past);
}